// Round 1
// baseline (719.834 us; speedup 1.0000x reference)
//
#include <hip/hip_runtime.h>

typedef __attribute__((ext_vector_type(8))) short  s16x8;
typedef __attribute__((ext_vector_type(8))) unsigned short u16x8;
typedef __attribute__((ext_vector_type(4))) float  f32x4;

#define D_MODEL 1024
#define N_HEADS 16
#define D_HEAD  64
#define BATCH   2
#define SEQ     2048
#define M_TOK   4096   // BATCH*SEQ

// ---------------- ws layout (ushort element offsets) ----------------
#define OFF_XQ  0u
#define OFF_XK  4194304u
#define OFF_XV  8388608u
#define OFF_XC  12582912u
#define OFF_WT  16777216u            // 7 x 1048576 : Wq,Wqb,Wk,Wkg,Wv,Wvb,Wo (transposed [n][k])
#define OFF_QH  24117248u            // [B][H][T][64] bf16
#define OFF_KH  28311552u
#define OFF_VH  32505856u
#define OFF_OH  36700160u            // [B*T][1024] bf16

__device__ __forceinline__ unsigned short f2bf(float f) {
    unsigned int u = __builtin_bit_cast(unsigned int, f);
    u += 0x7FFFu + ((u >> 16) & 1u);
    return (unsigned short)(u >> 16);
}

__device__ __forceinline__ void gload16(const void* g, void* l) {
    __builtin_amdgcn_global_load_lds(
        (const __attribute__((address_space(1))) unsigned int*)g,
        (__attribute__((address_space(3))) unsigned int*)l, 16, 0, 0);
}

__device__ __forceinline__ f32x4 mfma16(s16x8 a, s16x8 b, f32x4 c) {
    return __builtin_amdgcn_mfma_f32_16x16x32_bf16(a, b, c, 0, 0, 0);
}

__device__ __forceinline__ f32x4 zero4() {
    f32x4 z; z[0] = 0.f; z[1] = 0.f; z[2] = 0.f; z[3] = 0.f; return z;
}

// ---------------- conversion kernels ----------------
struct P4 { const float* p[4]; };
struct P7 { const float* p[7]; };

__global__ __launch_bounds__(256) void cvt4(P4 srcs, unsigned short* dst) {
    const int a = blockIdx.y;
    const float* s = srcs.p[a];
    unsigned short* d = dst + ((size_t)a << 22);
    const size_t i = (((size_t)blockIdx.x << 8) + threadIdx.x) << 3;
    const float4 v0 = *(const float4*)(s + i);
    const float4 v1 = *(const float4*)(s + i + 4);
    u16x8 o;
    o[0] = f2bf(v0.x); o[1] = f2bf(v0.y); o[2] = f2bf(v0.z); o[3] = f2bf(v0.w);
    o[4] = f2bf(v1.x); o[5] = f2bf(v1.y); o[6] = f2bf(v1.z); o[7] = f2bf(v1.w);
    *(u16x8*)(d + i) = o;
}

// transpose weights: Wt[n][k] = W[k][n], f32 -> bf16
__global__ __launch_bounds__(256) void wtr(P7 srcs, unsigned short* dst) {
    const int z = blockIdx.z;
    const float* W = srcs.p[z];
    unsigned short* Wt = dst + ((size_t)z << 20);
    __shared__ float T[32][33];
    const int t = threadIdx.x;
    const int r = t >> 3, c4 = (t & 7) << 2;
    const int kt = blockIdx.y << 5, nt = blockIdx.x << 5;
    const float4 v = *(const float4*)(W + ((size_t)(kt + r) << 10) + nt + c4);
    T[r][c4] = v.x; T[r][c4 + 1] = v.y; T[r][c4 + 2] = v.z; T[r][c4 + 3] = v.w;
    __syncthreads();
    ushort4 o;
    o.x = f2bf(T[c4 + 0][r]); o.y = f2bf(T[c4 + 1][r]);
    o.z = f2bf(T[c4 + 2][r]); o.w = f2bf(T[c4 + 3][r]);
    *(ushort4*)(Wt + ((size_t)(nt + r) << 10) + kt + c4) = o;
}

// ---------------- projection GEMMs (128x128 tile, 4 waves, 16x16x32 MFMA) ----------------
// C[m][n] = sum_k A0[m][k]*B0t[n][k] + sum_k A1[m][k]*B1t[n][k] + bias0[n]+bias1[n]
// dst layout: [B][H][T][64] bf16
__global__ __launch_bounds__(256) void proj_concat(
    const unsigned short* __restrict__ A0, const unsigned short* __restrict__ A1,
    const unsigned short* __restrict__ B0, const unsigned short* __restrict__ B1,
    const float* __restrict__ bias0, const float* __restrict__ bias1,
    unsigned short* __restrict__ dst)
{
    __shared__ unsigned short Al[128 * 32];
    __shared__ unsigned short Bl[128 * 32];
    const int tid = threadIdx.x;
    const int wid = tid >> 6, lane = tid & 63;
    const int lo = lane & 15, hi = lane >> 4;
    const int wr = wid >> 1, wc = wid & 1;
    const int m0 = blockIdx.y << 7, n0 = blockIdx.x << 7;

    f32x4 acc[4][4];
    #pragma unroll
    for (int i = 0; i < 4; ++i)
        #pragma unroll
        for (int j = 0; j < 4; ++j) acc[i][j] = zero4();

    for (int kt = 0; kt < 64; ++kt) {
        const unsigned short* As = (kt < 32) ? A0 : A1;
        const unsigned short* Bs = (kt < 32) ? B0 : B1;
        const int k0 = (kt & 31) << 5;
        __syncthreads();
        #pragma unroll
        for (int j = 0; j < 2; ++j) {
            const int cb = j * 256 + wid * 64;
            const int c = cb + lane;
            const int r = c >> 2, jj = c & 3;
            gload16(As + ((size_t)(m0 + r) << 10) + k0 + jj * 8, Al + cb * 8);
            gload16(Bs + ((size_t)(n0 + r) << 10) + k0 + jj * 8, Bl + cb * 8);
        }
        __syncthreads();
        s16x8 af[4], bf[4];
        #pragma unroll
        for (int mi = 0; mi < 4; ++mi)
            af[mi] = *(const s16x8*)&Al[(wr * 64 + mi * 16 + lo) * 32 + hi * 8];
        #pragma unroll
        for (int ni = 0; ni < 4; ++ni)
            bf[ni] = *(const s16x8*)&Bl[(wc * 64 + ni * 16 + lo) * 32 + hi * 8];
        #pragma unroll
        for (int mi = 0; mi < 4; ++mi)
            #pragma unroll
            for (int ni = 0; ni < 4; ++ni)
                acc[mi][ni] = mfma16(af[mi], bf[ni], acc[mi][ni]);
    }

    #pragma unroll
    for (int mi = 0; mi < 4; ++mi)
        #pragma unroll
        for (int ni = 0; ni < 4; ++ni) {
            const int n = n0 + wc * 64 + ni * 16 + lo;
            const float bsum = bias0[n] + bias1[n];
            const int h = n >> 6, d = n & 63;
            #pragma unroll
            for (int reg = 0; reg < 4; ++reg) {
                const int m = m0 + wr * 64 + mi * 16 + hi * 4 + reg;
                const int b = m >> 11, t = m & 2047;
                dst[((size_t)((b * 16 + h) * 2048 + t) << 6) + d] =
                    f2bf(acc[mi][ni][reg] + bsum);
            }
        }
}

// Kh = (keys@Wk + bk) * sigmoid(context@Wkg + bkg)
__global__ __launch_bounds__(256) void proj_kgate(
    const unsigned short* __restrict__ A0, const unsigned short* __restrict__ A1,
    const unsigned short* __restrict__ B0, const unsigned short* __restrict__ B1,
    const float* __restrict__ bias0, const float* __restrict__ bias1,
    unsigned short* __restrict__ dst)
{
    __shared__ unsigned short Al[128 * 32];
    __shared__ unsigned short Bl[128 * 32];
    const int tid = threadIdx.x;
    const int wid = tid >> 6, lane = tid & 63;
    const int lo = lane & 15, hi = lane >> 4;
    const int wr = wid >> 1, wc = wid & 1;
    const int m0 = blockIdx.y << 7, n0 = blockIdx.x << 7;

    f32x4 acc0[4][4], acc1[4][4];
    #pragma unroll
    for (int i = 0; i < 4; ++i)
        #pragma unroll
        for (int j = 0; j < 4; ++j) { acc0[i][j] = zero4(); acc1[i][j] = zero4(); }

    auto do_half = [&](const unsigned short* As, const unsigned short* Bs,
                       f32x4 (&acc)[4][4]) {
        for (int kt = 0; kt < 32; ++kt) {
            const int k0 = kt << 5;
            __syncthreads();
            #pragma unroll
            for (int j = 0; j < 2; ++j) {
                const int cb = j * 256 + wid * 64;
                const int c = cb + lane;
                const int r = c >> 2, jj = c & 3;
                gload16(As + ((size_t)(m0 + r) << 10) + k0 + jj * 8, Al + cb * 8);
                gload16(Bs + ((size_t)(n0 + r) << 10) + k0 + jj * 8, Bl + cb * 8);
            }
            __syncthreads();
            s16x8 af[4], bf[4];
            #pragma unroll
            for (int mi = 0; mi < 4; ++mi)
                af[mi] = *(const s16x8*)&Al[(wr * 64 + mi * 16 + lo) * 32 + hi * 8];
            #pragma unroll
            for (int ni = 0; ni < 4; ++ni)
                bf[ni] = *(const s16x8*)&Bl[(wc * 64 + ni * 16 + lo) * 32 + hi * 8];
            #pragma unroll
            for (int mi = 0; mi < 4; ++mi)
                #pragma unroll
                for (int ni = 0; ni < 4; ++ni)
                    acc[mi][ni] = mfma16(af[mi], bf[ni], acc[mi][ni]);
        }
    };
    do_half(A0, B0, acc0);
    do_half(A1, B1, acc1);

    #pragma unroll
    for (int mi = 0; mi < 4; ++mi)
        #pragma unroll
        for (int ni = 0; ni < 4; ++ni) {
            const int n = n0 + wc * 64 + ni * 16 + lo;
            const float b0 = bias0[n], b1 = bias1[n];
            const int h = n >> 6, d = n & 63;
            #pragma unroll
            for (int reg = 0; reg < 4; ++reg) {
                const int m = m0 + wr * 64 + mi * 16 + hi * 4 + reg;
                const int b = m >> 11, t = m & 2047;
                const float kv = acc0[mi][ni][reg] + b0;
                const float gv = acc1[mi][ni][reg] + b1;
                const float sg = 1.0f / (1.0f + __expf(-gv));
                dst[((size_t)((b * 16 + h) * 2048 + t) << 6) + d] = f2bf(kv * sg);
            }
        }
}

// out0 = Oh @ Wo + bo  (f32 output)
__global__ __launch_bounds__(256) void gemm_out(
    const unsigned short* __restrict__ A, const unsigned short* __restrict__ Bt,
    const float* __restrict__ bias, float* __restrict__ out)
{
    __shared__ unsigned short Al[128 * 32];
    __shared__ unsigned short Bl[128 * 32];
    const int tid = threadIdx.x;
    const int wid = tid >> 6, lane = tid & 63;
    const int lo = lane & 15, hi = lane >> 4;
    const int wr = wid >> 1, wc = wid & 1;
    const int m0 = blockIdx.y << 7, n0 = blockIdx.x << 7;

    f32x4 acc[4][4];
    #pragma unroll
    for (int i = 0; i < 4; ++i)
        #pragma unroll
        for (int j = 0; j < 4; ++j) acc[i][j] = zero4();

    for (int kt = 0; kt < 32; ++kt) {
        const int k0 = kt << 5;
        __syncthreads();
        #pragma unroll
        for (int j = 0; j < 2; ++j) {
            const int cb = j * 256 + wid * 64;
            const int c = cb + lane;
            const int r = c >> 2, jj = c & 3;
            gload16(A + ((size_t)(m0 + r) << 10) + k0 + jj * 8, Al + cb * 8);
            gload16(Bt + ((size_t)(n0 + r) << 10) + k0 + jj * 8, Bl + cb * 8);
        }
        __syncthreads();
        s16x8 af[4], bf[4];
        #pragma unroll
        for (int mi = 0; mi < 4; ++mi)
            af[mi] = *(const s16x8*)&Al[(wr * 64 + mi * 16 + lo) * 32 + hi * 8];
        #pragma unroll
        for (int ni = 0; ni < 4; ++ni)
            bf[ni] = *(const s16x8*)&Bl[(wc * 64 + ni * 16 + lo) * 32 + hi * 8];
        #pragma unroll
        for (int mi = 0; mi < 4; ++mi)
            #pragma unroll
            for (int ni = 0; ni < 4; ++ni)
                acc[mi][ni] = mfma16(af[mi], bf[ni], acc[mi][ni]);
    }

    #pragma unroll
    for (int mi = 0; mi < 4; ++mi)
        #pragma unroll
        for (int ni = 0; ni < 4; ++ni) {
            const int n = n0 + wc * 64 + ni * 16 + lo;
            const float bb = bias[n];
            #pragma unroll
            for (int reg = 0; reg < 4; ++reg) {
                const int m = m0 + wr * 64 + mi * 16 + hi * 4 + reg;
                out[((size_t)m << 10) + n] = acc[mi][ni][reg] + bb;
            }
        }
}

// ---------------- fused attention ----------------
// grid (16, 32): x = 128-row Q tile, y = b*16+h. 256 threads, 4 waves.
// Two-pass: pass0 online max/sum, pass1 recompute -> write weights f32 + PV.
__global__ __launch_bounds__(256) void attn_fused(
    const unsigned short* __restrict__ Qh, const unsigned short* __restrict__ Kh,
    const unsigned short* __restrict__ Vh, const unsigned char* __restrict__ maskp,
    float* __restrict__ attnW, unsigned short* __restrict__ Oh)
{
    __shared__ unsigned short Qs[128 * 64];
    __shared__ unsigned short Ks[64 * 64];
    __shared__ unsigned short Vt[64 * 64];       // transposed V tile [d][s]
    __shared__ unsigned short Ws[4][32 * 64];    // per-wave P tile
    __shared__ unsigned char  Msk[128 * 64];

    const int tid = threadIdx.x;
    const int wid = tid >> 6, lane = tid & 63;
    const int lo = lane & 15, hi = lane >> 4;
    const int lt = blockIdx.x, bh = blockIdx.y;
    const int b = bh >> 4, hh = bh & 15;
    const int l0 = lt << 7;

    const unsigned short* Qp = Qh + ((size_t)bh * 2048 + l0) * 64;
    const unsigned short* Kp = Kh + (size_t)bh * 2048 * 64;
    const unsigned short* Vp = Vh + (size_t)bh * 2048 * 64;
    float* Wout = attnW + ((size_t)bh * 2048 + l0) * 2048;
    const size_t mrowbase = (size_t)b * 2048 + l0;

    // mask dtype autodetect: int32 iff first 64 dwords all <= 1
    const unsigned int mv = ((const unsigned int*)maskp)[lane];
    const bool isInt = __all(mv <= 1u);

    // ---- stage Q (swizzled: 16B chunk j ^= row&7) ----
    #pragma unroll
    for (int it = 0; it < 4; ++it) {
        const int cb = it * 256 + wid * 64;
        const int c = cb + lane;
        const int r = c >> 3, j = c & 7;
        gload16(Qp + (size_t)r * 64 + ((j ^ (r & 7)) << 3), Qs + cb * 8);
    }
    __syncthreads();
    s16x8 qf[2][2];
    #pragma unroll
    for (int mi = 0; mi < 2; ++mi)
        #pragma unroll
        for (int ks = 0; ks < 2; ++ks) {
            const int row = wid * 32 + mi * 16 + lo;
            qf[mi][ks] = *(const s16x8*)&Qs[row * 64 + (((hi + ks * 4) ^ (row & 7)) << 3)];
        }

    float m_[2][4], l_[2][4];
    #pragma unroll
    for (int mi = 0; mi < 2; ++mi)
        #pragma unroll
        for (int r = 0; r < 4; ++r) { m_[mi][r] = -INFINITY; l_[mi][r] = 0.f; }

    // ================= pass 0: stats =================
    for (int st = 0; st < 32; ++st) {
        const int s0 = st << 6;
        __syncthreads();
        #pragma unroll
        for (int it = 0; it < 2; ++it) {
            const int cb = it * 256 + wid * 64;
            const int c = cb + lane;
            const int r = c >> 3, j = c & 7;
            gload16(Kp + (size_t)(s0 + r) * 64 + ((j ^ (r & 7)) << 3), Ks + cb * 8);
        }
        {
            const int row = tid >> 1, half = tid & 1;
            unsigned int* mrow = (unsigned int*)&Msk[row * 64 + half * 32];
            const size_t base = (mrowbase + row) * 2048 + s0 + half * 32;
            if (isInt) {
                const int* mi32 = (const int*)maskp;
                #pragma unroll
                for (int i = 0; i < 8; ++i) {
                    const uint4 v = *(const uint4*)(mi32 + base + i * 4);
                    mrow[i] = (v.x ? 1u : 0u) | ((v.y ? 1u : 0u) << 8) |
                              ((v.z ? 1u : 0u) << 16) | ((v.w ? 1u : 0u) << 24);
                }
            } else {
                #pragma unroll
                for (int i = 0; i < 8; ++i)
                    mrow[i] = *(const unsigned int*)(maskp + base + i * 4);
            }
        }
        __syncthreads();

        f32x4 sf[2][4];
        #pragma unroll
        for (int mi = 0; mi < 2; ++mi)
            #pragma unroll
            for (int ni = 0; ni < 4; ++ni) sf[mi][ni] = zero4();
        #pragma unroll
        for (int ks = 0; ks < 2; ++ks)
            #pragma unroll
            for (int ni = 0; ni < 4; ++ni) {
                const int rn = ni * 16 + lo;
                const s16x8 kf = *(const s16x8*)&Ks[rn * 64 + (((hi + ks * 4) ^ (rn & 7)) << 3)];
                sf[0][ni] = mfma16(qf[0][ks], kf, sf[0][ni]);
                sf[1][ni] = mfma16(qf[1][ks], kf, sf[1][ni]);
            }
        #pragma unroll
        for (int mi = 0; mi < 2; ++mi)
            #pragma unroll
            for (int ni = 0; ni < 4; ++ni)
                #pragma unroll
                for (int reg = 0; reg < 4; ++reg) {
                    const int row = wid * 32 + mi * 16 + hi * 4 + reg;
                    const int col = ni * 16 + lo;
                    float v = sf[mi][ni][reg] * 0.125f;
                    if (Msk[row * 64 + col]) v = -1e9f;
                    sf[mi][ni][reg] = v;
                }
        #pragma unroll
        for (int mi = 0; mi < 2; ++mi)
            #pragma unroll
            for (int reg = 0; reg < 4; ++reg) {
                float tm = fmaxf(fmaxf(sf[mi][0][reg], sf[mi][1][reg]),
                                 fmaxf(sf[mi][2][reg], sf[mi][3][reg]));
                tm = fmaxf(tm, __shfl_xor(tm, 1));
                tm = fmaxf(tm, __shfl_xor(tm, 2));
                tm = fmaxf(tm, __shfl_xor(tm, 4));
                tm = fmaxf(tm, __shfl_xor(tm, 8));
                const float mn = fmaxf(m_[mi][reg], tm);
                float p = __expf(sf[mi][0][reg] - mn) + __expf(sf[mi][1][reg] - mn) +
                          __expf(sf[mi][2][reg] - mn) + __expf(sf[mi][3][reg] - mn);
                p += __shfl_xor(p, 1);
                p += __shfl_xor(p, 2);
                p += __shfl_xor(p, 4);
                p += __shfl_xor(p, 8);
                l_[mi][reg] = l_[mi][reg] * __expf(m_[mi][reg] - mn) + p;
                m_[mi][reg] = mn;
            }
    }

    float il[2][4];
    #pragma unroll
    for (int mi = 0; mi < 2; ++mi)
        #pragma unroll
        for (int reg = 0; reg < 4; ++reg) il[mi][reg] = 1.0f / l_[mi][reg];

    f32x4 oacc[2][4];
    #pragma unroll
    for (int mi = 0; mi < 2; ++mi)
        #pragma unroll
        for (int nd = 0; nd < 4; ++nd) oacc[mi][nd] = zero4();

    // ================= pass 1: weights + PV =================
    for (int st = 0; st < 32; ++st) {
        const int s0 = st << 6;
        __syncthreads();
        #pragma unroll
        for (int it = 0; it < 2; ++it) {
            const int cb = it * 256 + wid * 64;
            const int c = cb + lane;
            const int r = c >> 3, j = c & 7;
            gload16(Kp + (size_t)(s0 + r) * 64 + ((j ^ (r & 7)) << 3), Ks + cb * 8);
        }
        {
            const int row = tid >> 1, half = tid & 1;
            unsigned int* mrow = (unsigned int*)&Msk[row * 64 + half * 32];
            const size_t base = (mrowbase + row) * 2048 + s0 + half * 32;
            if (isInt) {
                const int* mi32 = (const int*)maskp;
                #pragma unroll
                for (int i = 0; i < 8; ++i) {
                    const uint4 v = *(const uint4*)(mi32 + base + i * 4);
                    mrow[i] = (v.x ? 1u : 0u) | ((v.y ? 1u : 0u) << 8) |
                              ((v.z ? 1u : 0u) << 16) | ((v.w ? 1u : 0u) << 24);
                }
            } else {
                #pragma unroll
                for (int i = 0; i < 8; ++i)
                    mrow[i] = *(const unsigned int*)(maskp + base + i * 4);
            }
        }
        #pragma unroll
        for (int it = 0; it < 2; ++it) {
            const int c = it * 256 + tid;
            const int s = c >> 3, d0 = (c & 7) << 3;
            const u16x8 v = *(const u16x8*)(Vp + (size_t)(s0 + s) * 64 + d0);
            #pragma unroll
            for (int i = 0; i < 8; ++i) {
                const int d = d0 + i;
                Vt[d * 64 + ((((s >> 3) ^ (d & 7)) << 3) | (s & 7))] = v[i];
            }
        }
        __syncthreads();

        f32x4 sf[2][4];
        #pragma unroll
        for (int mi = 0; mi < 2; ++mi)
            #pragma unroll
            for (int ni = 0; ni < 4; ++ni) sf[mi][ni] = zero4();
        #pragma unroll
        for (int ks = 0; ks < 2; ++ks)
            #pragma unroll
            for (int ni = 0; ni < 4; ++ni) {
                const int rn = ni * 16 + lo;
                const s16x8 kf = *(const s16x8*)&Ks[rn * 64 + (((hi + ks * 4) ^ (rn & 7)) << 3)];
                sf[0][ni] = mfma16(qf[0][ks], kf, sf[0][ni]);
                sf[1][ni] = mfma16(qf[1][ks], kf, sf[1][ni]);
            }
        #pragma unroll
        for (int mi = 0; mi < 2; ++mi)
            #pragma unroll
            for (int ni = 0; ni < 4; ++ni)
                #pragma unroll
                for (int reg = 0; reg < 4; ++reg) {
                    const int rloc = mi * 16 + hi * 4 + reg;
                    const int row = wid * 32 + rloc;
                    const int col = ni * 16 + lo;
                    float v = sf[mi][ni][reg] * 0.125f;
                    if (Msk[row * 64 + col]) v = -1e9f;
                    const float w = __expf(v - m_[mi][reg]) * il[mi][reg];
                    Wout[(size_t)row * 2048 + s0 + col] = w;
                    Ws[wid][rloc * 64 + ((((col >> 3) ^ (rloc & 7)) << 3) | (col & 7))] = f2bf(w);
                }
        // PV: oacc[mi][nd] += P[32xKT] @ V[KTx64]
        #pragma unroll
        for (int ks = 0; ks < 2; ++ks) {
            s16x8 wf[2];
            #pragma unroll
            for (int mi = 0; mi < 2; ++mi) {
                const int rw = mi * 16 + lo;
                wf[mi] = *(const s16x8*)&Ws[wid][rw * 64 + (((hi + ks * 4) ^ (rw & 7)) << 3)];
            }
            #pragma unroll
            for (int nd = 0; nd < 4; ++nd) {
                const int rv = nd * 16 + lo;
                const s16x8 vf = *(const s16x8*)&Vt[rv * 64 + (((hi + ks * 4) ^ (rv & 7)) << 3)];
                oacc[0][nd] = mfma16(wf[0], vf, oacc[0][nd]);
                oacc[1][nd] = mfma16(wf[1], vf, oacc[1][nd]);
            }
        }
    }

    // ---- epilogue: Oh[b*2048 + l][h*64 + d] ----
    #pragma unroll
    for (int mi = 0; mi < 2; ++mi)
        #pragma unroll
        for (int nd = 0; nd < 4; ++nd)
            #pragma unroll
            for (int reg = 0; reg < 4; ++reg) {
                const int rl = wid * 32 + mi * 16 + hi * 4 + reg;
                const int d = nd * 16 + lo;
                Oh[((size_t)(b * 2048 + l0 + rl) << 10) + hh * 64 + d] =
                    f2bf(oacc[mi][nd][reg]);
            }
}

// ---------------- launch ----------------
extern "C" void kernel_launch(void* const* d_in, const int* in_sizes, int n_in,
                              void* d_out, int out_size, void* d_ws, size_t ws_size,
                              hipStream_t stream) {
    const float* queries = (const float*)d_in[0];
    const float* keys    = (const float*)d_in[1];
    const float* values  = (const float*)d_in[2];
    const unsigned char* mask = (const unsigned char*)d_in[3];
    const float* context = (const float*)d_in[4];
    const float* Wq  = (const float*)d_in[5];  const float* bq  = (const float*)d_in[6];
    const float* Wk  = (const float*)d_in[7];  const float* bk  = (const float*)d_in[8];
    const float* Wv  = (const float*)d_in[9];  const float* bv  = (const float*)d_in[10];
    const float* Wqb = (const float*)d_in[11]; const float* bqb = (const float*)d_in[12];
    const float* Wkg = (const float*)d_in[13]; const float* bkg = (const float*)d_in[14];
    const float* Wvb = (const float*)d_in[15]; const float* bvb = (const float*)d_in[16];
    const float* Wo  = (const float*)d_in[17]; const float* bo  = (const float*)d_in[18];

    unsigned short* ws = (unsigned short*)d_ws;
    unsigned short* xq = ws + OFF_XQ;
    unsigned short* xk = ws + OFF_XK;
    unsigned short* xv = ws + OFF_XV;
    unsigned short* xc = ws + OFF_XC;
    unsigned short* wt = ws + OFF_WT;   // 0:Wq 1:Wqb 2:Wk 3:Wkg 4:Wv 5:Wvb 6:Wo (transposed)
    unsigned short* Qh = ws + OFF_QH;
    unsigned short* Kh = ws + OFF_KH;
    unsigned short* Vh = ws + OFF_VH;
    unsigned short* Oh = ws + OFF_OH;

    float* out0  = (float*)d_out;
    float* attnW = out0 + 4194304;

    P4 acts; acts.p[0] = queries; acts.p[1] = keys; acts.p[2] = values; acts.p[3] = context;
    cvt4<<<dim3(2048, 4), 256, 0, stream>>>(acts, xq);

    P7 wts; wts.p[0] = Wq; wts.p[1] = Wqb; wts.p[2] = Wk; wts.p[3] = Wkg;
    wts.p[4] = Wv; wts.p[5] = Wvb; wts.p[6] = Wo;
    wtr<<<dim3(32, 32, 7), 256, 0, stream>>>(wts, wt);

    proj_concat<<<dim3(8, 32), 256, 0, stream>>>(xq, xc, wt, wt + 1048576, bq, bqb, Qh);
    proj_concat<<<dim3(8, 32), 256, 0, stream>>>(xv, xc, wt + 4u * 1048576, wt + 5u * 1048576, bv, bvb, Vh);
    proj_kgate<<<dim3(8, 32), 256, 0, stream>>>(xk, xc, wt + 2u * 1048576, wt + 3u * 1048576, bk, bkg, Kh);

    attn_fused<<<dim3(16, 32), 256, 0, stream>>>(Qh, Kh, Vh, mask, attnW, Oh);

    gemm_out<<<dim3(8, 32), 256, 0, stream>>>(Oh, wt + 6u * 1048576, bo, out0);
}

// Round 2
// 396.505 us; speedup vs baseline: 1.8154x; 1.8154x over previous
//
#include <hip/hip_runtime.h>

typedef __attribute__((ext_vector_type(8))) short  s16x8;
typedef __attribute__((ext_vector_type(8))) unsigned short u16x8;
typedef __attribute__((ext_vector_type(4))) float  f32x4;

#define D_MODEL 1024
#define N_HEADS 16
#define D_HEAD  64
#define BATCH   2
#define SEQ     2048
#define M_TOK   4096   // BATCH*SEQ

// ---------------- ws layout (ushort element offsets) ----------------
#define OFF_XQ  0u            // 4M u16; reused for VhT after projections
#define OFF_XK  4194304u
#define OFF_XV  8388608u      // reused for mask bitmask after V projection
#define OFF_XC  12582912u
#define OFF_WT  16777216u     // 7 x 1048576 : Wq,Wqb,Wk,Wkg,Wv,Wvb,Wo (transposed [n][k])
#define OFF_QH  24117248u     // [B][H][T][64] bf16 (pre-scaled by 1/8)
#define OFF_KH  28311552u
#define OFF_VH  32505856u
#define OFF_OH  36700160u     // [B*T][1024] bf16

__device__ __forceinline__ unsigned short f2bf(float f) {
    unsigned int u = __builtin_bit_cast(unsigned int, f);
    u += 0x7FFFu + ((u >> 16) & 1u);
    return (unsigned short)(u >> 16);
}

__device__ __forceinline__ void gload16(const void* g, void* l) {
    __builtin_amdgcn_global_load_lds(
        (const __attribute__((address_space(1))) unsigned int*)g,
        (__attribute__((address_space(3))) unsigned int*)l, 16, 0, 0);
}

__device__ __forceinline__ f32x4 mfma16(s16x8 a, s16x8 b, f32x4 c) {
    return __builtin_amdgcn_mfma_f32_16x16x32_bf16(a, b, c, 0, 0, 0);
}

__device__ __forceinline__ f32x4 zero4() {
    f32x4 z; z[0] = 0.f; z[1] = 0.f; z[2] = 0.f; z[3] = 0.f; return z;
}

// ---------------- conversion kernels ----------------
struct P4 { const float* p[4]; };
struct P7 { const float* p[7]; };

__global__ __launch_bounds__(256) void cvt4(P4 srcs, unsigned short* dst) {
    const int a = blockIdx.y;
    const float* s = srcs.p[a];
    unsigned short* d = dst + ((size_t)a << 22);
    const size_t i = (((size_t)blockIdx.x << 8) + threadIdx.x) << 3;
    const float4 v0 = *(const float4*)(s + i);
    const float4 v1 = *(const float4*)(s + i + 4);
    u16x8 o;
    o[0] = f2bf(v0.x); o[1] = f2bf(v0.y); o[2] = f2bf(v0.z); o[3] = f2bf(v0.w);
    o[4] = f2bf(v1.x); o[5] = f2bf(v1.y); o[6] = f2bf(v1.z); o[7] = f2bf(v1.w);
    *(u16x8*)(d + i) = o;
}

// transpose weights: Wt[n][k] = W[k][n], f32 -> bf16
__global__ __launch_bounds__(256) void wtr(P7 srcs, unsigned short* dst) {
    const int z = blockIdx.z;
    const float* W = srcs.p[z];
    unsigned short* Wt = dst + ((size_t)z << 20);
    __shared__ float T[32][33];
    const int t = threadIdx.x;
    const int r = t >> 3, c4 = (t & 7) << 2;
    const int kt = blockIdx.y << 5, nt = blockIdx.x << 5;
    const float4 v = *(const float4*)(W + ((size_t)(kt + r) << 10) + nt + c4);
    T[r][c4] = v.x; T[r][c4 + 1] = v.y; T[r][c4 + 2] = v.z; T[r][c4 + 3] = v.w;
    __syncthreads();
    ushort4 o;
    o.x = f2bf(T[c4 + 0][r]); o.y = f2bf(T[c4 + 1][r]);
    o.z = f2bf(T[c4 + 2][r]); o.w = f2bf(T[c4 + 3][r]);
    *(ushort4*)(Wt + ((size_t)(nt + r) << 10) + kt + c4) = o;
}

// V head-transpose: VhT[bh][d][s] = Vh[bh][s][d]
__global__ __launch_bounds__(256) void vtr(const unsigned short* __restrict__ Vh,
                                           unsigned short* __restrict__ VhT) {
    __shared__ unsigned short T[64][72];
    const int bh = blockIdx.y, s0 = blockIdx.x << 6;
    const unsigned short* src = Vh + ((size_t)bh * 2048 + s0) * 64;
    unsigned short* dst = VhT + (size_t)bh * 64 * 2048 + s0;
    const int t = threadIdx.x;
    const int r = t >> 3, c0 = (t & 7) << 3;
    #pragma unroll
    for (int it = 0; it < 2; ++it) {
        const int rr = it * 32 + r;
        const u16x8 v = *(const u16x8*)(src + (size_t)rr * 64 + c0);
        #pragma unroll
        for (int i = 0; i < 8; ++i) T[c0 + i][rr] = v[i];
    }
    __syncthreads();
    #pragma unroll
    for (int it = 0; it < 2; ++it) {
        const int rr = it * 32 + r;
        u16x8 o;
        #pragma unroll
        for (int i = 0; i < 8; ++i) o[i] = T[rr][c0 + i];
        *(u16x8*)(dst + (size_t)rr * 2048 + c0) = o;
    }
}

// pack mask to bits: bit i of mb[w] = mask[w*64+i] != 0. Autodetect int32 vs byte.
__global__ __launch_bounds__(256) void mpack(const unsigned char* __restrict__ maskp,
                                             unsigned long long* __restrict__ mb) {
    const unsigned int probe = ((const unsigned int*)maskp)[threadIdx.x & 63];
    const bool isInt = __all(probe <= 1u);
    const size_t i = ((size_t)blockIdx.x << 8) + threadIdx.x;
    bool v;
    if (isInt) v = ((const int*)maskp)[i] != 0;
    else       v = maskp[i] != 0;
    const unsigned long long bal = __ballot(v);
    if ((threadIdx.x & 63) == 0) mb[i >> 6] = bal;
}

// ---------------- projection GEMMs (128x128 tile, 4 waves, 16x16x32 MFMA) ----------------
__global__ __launch_bounds__(256) void proj_concat(
    const unsigned short* __restrict__ A0, const unsigned short* __restrict__ A1,
    const unsigned short* __restrict__ B0, const unsigned short* __restrict__ B1,
    const float* __restrict__ bias0, const float* __restrict__ bias1,
    unsigned short* __restrict__ dst, float oscale)
{
    __shared__ unsigned short Al[128 * 32];
    __shared__ unsigned short Bl[128 * 32];
    const int tid = threadIdx.x;
    const int wid = tid >> 6, lane = tid & 63;
    const int lo = lane & 15, hi = lane >> 4;
    const int wr = wid >> 1, wc = wid & 1;
    const int m0 = blockIdx.y << 7, n0 = blockIdx.x << 7;

    f32x4 acc[4][4];
    #pragma unroll
    for (int i = 0; i < 4; ++i)
        #pragma unroll
        for (int j = 0; j < 4; ++j) acc[i][j] = zero4();

    for (int kt = 0; kt < 64; ++kt) {
        const unsigned short* As = (kt < 32) ? A0 : A1;
        const unsigned short* Bs = (kt < 32) ? B0 : B1;
        const int k0 = (kt & 31) << 5;
        __syncthreads();
        #pragma unroll
        for (int j = 0; j < 2; ++j) {
            const int cb = j * 256 + wid * 64;
            const int c = cb + lane;
            const int r = c >> 2, jj = c & 3;
            gload16(As + ((size_t)(m0 + r) << 10) + k0 + jj * 8, Al + cb * 8);
            gload16(Bs + ((size_t)(n0 + r) << 10) + k0 + jj * 8, Bl + cb * 8);
        }
        __syncthreads();
        s16x8 af[4], bf[4];
        #pragma unroll
        for (int mi = 0; mi < 4; ++mi)
            af[mi] = *(const s16x8*)&Al[(wr * 64 + mi * 16 + lo) * 32 + hi * 8];
        #pragma unroll
        for (int ni = 0; ni < 4; ++ni)
            bf[ni] = *(const s16x8*)&Bl[(wc * 64 + ni * 16 + lo) * 32 + hi * 8];
        #pragma unroll
        for (int mi = 0; mi < 4; ++mi)
            #pragma unroll
            for (int ni = 0; ni < 4; ++ni)
                acc[mi][ni] = mfma16(af[mi], bf[ni], acc[mi][ni]);
    }

    #pragma unroll
    for (int mi = 0; mi < 4; ++mi)
        #pragma unroll
        for (int ni = 0; ni < 4; ++ni) {
            const int n = n0 + wc * 64 + ni * 16 + lo;
            const float bsum = bias0[n] + bias1[n];
            const int h = n >> 6, d = n & 63;
            #pragma unroll
            for (int reg = 0; reg < 4; ++reg) {
                const int m = m0 + wr * 64 + mi * 16 + hi * 4 + reg;
                const int b = m >> 11, t = m & 2047;
                dst[((size_t)((b * 16 + h) * 2048 + t) << 6) + d] =
                    f2bf((acc[mi][ni][reg] + bsum) * oscale);
            }
        }
}

// Kh = (keys@Wk + bk) * sigmoid(context@Wkg + bkg)
__global__ __launch_bounds__(256) void proj_kgate(
    const unsigned short* __restrict__ A0, const unsigned short* __restrict__ A1,
    const unsigned short* __restrict__ B0, const unsigned short* __restrict__ B1,
    const float* __restrict__ bias0, const float* __restrict__ bias1,
    unsigned short* __restrict__ dst)
{
    __shared__ unsigned short Al[128 * 32];
    __shared__ unsigned short Bl[128 * 32];
    const int tid = threadIdx.x;
    const int wid = tid >> 6, lane = tid & 63;
    const int lo = lane & 15, hi = lane >> 4;
    const int wr = wid >> 1, wc = wid & 1;
    const int m0 = blockIdx.y << 7, n0 = blockIdx.x << 7;

    f32x4 acc0[4][4], acc1[4][4];
    #pragma unroll
    for (int i = 0; i < 4; ++i)
        #pragma unroll
        for (int j = 0; j < 4; ++j) { acc0[i][j] = zero4(); acc1[i][j] = zero4(); }

    auto do_half = [&](const unsigned short* As, const unsigned short* Bs,
                       f32x4 (&acc)[4][4]) {
        for (int kt = 0; kt < 32; ++kt) {
            const int k0 = kt << 5;
            __syncthreads();
            #pragma unroll
            for (int j = 0; j < 2; ++j) {
                const int cb = j * 256 + wid * 64;
                const int c = cb + lane;
                const int r = c >> 2, jj = c & 3;
                gload16(As + ((size_t)(m0 + r) << 10) + k0 + jj * 8, Al + cb * 8);
                gload16(Bs + ((size_t)(n0 + r) << 10) + k0 + jj * 8, Bl + cb * 8);
            }
            __syncthreads();
            s16x8 af[4], bf[4];
            #pragma unroll
            for (int mi = 0; mi < 4; ++mi)
                af[mi] = *(const s16x8*)&Al[(wr * 64 + mi * 16 + lo) * 32 + hi * 8];
            #pragma unroll
            for (int ni = 0; ni < 4; ++ni)
                bf[ni] = *(const s16x8*)&Bl[(wc * 64 + ni * 16 + lo) * 32 + hi * 8];
            #pragma unroll
            for (int mi = 0; mi < 4; ++mi)
                #pragma unroll
                for (int ni = 0; ni < 4; ++ni)
                    acc[mi][ni] = mfma16(af[mi], bf[ni], acc[mi][ni]);
        }
    };
    do_half(A0, B0, acc0);
    do_half(A1, B1, acc1);

    #pragma unroll
    for (int mi = 0; mi < 4; ++mi)
        #pragma unroll
        for (int ni = 0; ni < 4; ++ni) {
            const int n = n0 + wc * 64 + ni * 16 + lo;
            const float b0 = bias0[n], b1 = bias1[n];
            const int h = n >> 6, d = n & 63;
            #pragma unroll
            for (int reg = 0; reg < 4; ++reg) {
                const int m = m0 + wr * 64 + mi * 16 + hi * 4 + reg;
                const int b = m >> 11, t = m & 2047;
                const float kv = acc0[mi][ni][reg] + b0;
                const float gv = acc1[mi][ni][reg] + b1;
                const float sg = 1.0f / (1.0f + __expf(-gv));
                dst[((size_t)((b * 16 + h) * 2048 + t) << 6) + d] = f2bf(kv * sg);
            }
        }
}

// out0 = Oh @ Wo + bo  (f32 output)
__global__ __launch_bounds__(256) void gemm_out(
    const unsigned short* __restrict__ A, const unsigned short* __restrict__ Bt,
    const float* __restrict__ bias, float* __restrict__ out)
{
    __shared__ unsigned short Al[128 * 32];
    __shared__ unsigned short Bl[128 * 32];
    const int tid = threadIdx.x;
    const int wid = tid >> 6, lane = tid & 63;
    const int lo = lane & 15, hi = lane >> 4;
    const int wr = wid >> 1, wc = wid & 1;
    const int m0 = blockIdx.y << 7, n0 = blockIdx.x << 7;

    f32x4 acc[4][4];
    #pragma unroll
    for (int i = 0; i < 4; ++i)
        #pragma unroll
        for (int j = 0; j < 4; ++j) acc[i][j] = zero4();

    for (int kt = 0; kt < 32; ++kt) {
        const int k0 = kt << 5;
        __syncthreads();
        #pragma unroll
        for (int j = 0; j < 2; ++j) {
            const int cb = j * 256 + wid * 64;
            const int c = cb + lane;
            const int r = c >> 2, jj = c & 3;
            gload16(A + ((size_t)(m0 + r) << 10) + k0 + jj * 8, Al + cb * 8);
            gload16(Bt + ((size_t)(n0 + r) << 10) + k0 + jj * 8, Bl + cb * 8);
        }
        __syncthreads();
        s16x8 af[4], bf[4];
        #pragma unroll
        for (int mi = 0; mi < 4; ++mi)
            af[mi] = *(const s16x8*)&Al[(wr * 64 + mi * 16 + lo) * 32 + hi * 8];
        #pragma unroll
        for (int ni = 0; ni < 4; ++ni)
            bf[ni] = *(const s16x8*)&Bl[(wc * 64 + ni * 16 + lo) * 32 + hi * 8];
        #pragma unroll
        for (int mi = 0; mi < 4; ++mi)
            #pragma unroll
            for (int ni = 0; ni < 4; ++ni)
                acc[mi][ni] = mfma16(af[mi], bf[ni], acc[mi][ni]);
    }

    #pragma unroll
    for (int mi = 0; mi < 4; ++mi)
        #pragma unroll
        for (int ni = 0; ni < 4; ++ni) {
            const int n = n0 + wc * 64 + ni * 16 + lo;
            const float bb = bias[n];
            #pragma unroll
            for (int reg = 0; reg < 4; ++reg) {
                const int m = m0 + wr * 64 + mi * 16 + hi * 4 + reg;
                out[((size_t)m << 10) + n] = acc[mi][ni][reg] + bb;
            }
        }
}

// ---------------- fused attention ----------------
// 1024 blocks (XCD-chunked: each XCD gets contiguous bh range), 256 threads, 4 waves.
// Q-tile = 64 rows, each wave owns 16 rows. Two-pass, no-max softmax (scores bounded).
// K and V^T staged via global_load_lds (pre-swizzled source, linear LDS), double-buffered,
// one barrier per 64-col tile.
__global__ __launch_bounds__(256, 4) void attn_fused(
    const unsigned short* __restrict__ Qh, const unsigned short* __restrict__ Kh,
    const unsigned short* __restrict__ VhT, const unsigned long long* __restrict__ mbits,
    float* __restrict__ attnW, unsigned short* __restrict__ Oh)
{
    __shared__ unsigned short Ks[2][4096];   // [64 s][64 d], 16B chunks XOR-swizzled by row&7
    __shared__ unsigned short Vs[2][4096];   // [64 d][64 s], same swizzle
    __shared__ unsigned short Ps[4][1024];   // per-wave P [16 q][64 s], chunk ^= q&7

    const int tid = threadIdx.x;
    const int wid = tid >> 6, lane = tid & 63;
    const int lo = lane & 15, hi = lane >> 4;

    // XCD-chunked swizzle: 1024 = 8 XCD * 128; contiguous bh per XCD for K/V L2 reuse
    const int wg = blockIdx.x;
    const int gid = (wg & 7) * 128 + (wg >> 3);
    const int bh = gid >> 5, lt = gid & 31;
    const int b = bh >> 4, hh = bh & 15;
    const int l0 = lt << 6;

    const unsigned short* Qp = Qh + ((size_t)bh * 2048 + l0) * 64;
    const unsigned short* Kp = Kh + (size_t)bh * 2048 * 64;
    const unsigned short* Vp = VhT + (size_t)bh * 64 * 2048;
    float* Wout = attnW + ((size_t)bh * 2048 + l0) * 2048;
    const unsigned long long* mrb = mbits + ((size_t)b * 2048 + l0) * 32;

    // Q fragments direct from global (rows wid*16+lo; Q pre-scaled by 1/8)
    s16x8 qf[2];
    {
        const unsigned short* qr = Qp + (size_t)(wid * 16 + lo) * 64 + hi * 8;
        qf[0] = *(const s16x8*)qr;
        qf[1] = *(const s16x8*)(qr + 32);
    }

    auto stageK = [&](int st, int bufi) {
        const unsigned short* src = Kp + (size_t)(st << 6) * 64;
        #pragma unroll
        for (int it = 0; it < 2; ++it) {
            const int c = it * 256 + tid;
            const int r = c >> 3, j = c & 7;
            gload16(src + (size_t)r * 64 + ((j ^ (r & 7)) << 3), &Ks[bufi][c * 8]);
        }
    };
    auto stageV = [&](int st, int bufi) {
        const unsigned short* src = Vp + (st << 6);
        #pragma unroll
        for (int it = 0; it < 2; ++it) {
            const int c = it * 256 + tid;
            const int r = c >> 3, j = c & 7;
            gload16(src + (size_t)r * 2048 + ((j ^ (r & 7)) << 3), &Vs[bufi][c * 8]);
        }
    };

    // ================= pass 0: row sums of exp(s) (no max needed; scores bounded) ====
    float lsum[4] = {0.f, 0.f, 0.f, 0.f};
    stageK(0, 0);
    __syncthreads();
    for (int st = 0; st < 32; ++st) {
        const int cur = st & 1;
        if (st < 31) stageK(st + 1, cur ^ 1);

        f32x4 sf[4];
        #pragma unroll
        for (int ni = 0; ni < 4; ++ni) sf[ni] = zero4();
        #pragma unroll
        for (int ks = 0; ks < 2; ++ks)
            #pragma unroll
            for (int ni = 0; ni < 4; ++ni) {
                const int rn = ni * 16 + lo;
                const s16x8 kf = *(const s16x8*)&Ks[cur][rn * 64 + (((hi + ks * 4) ^ (rn & 7)) << 3)];
                sf[ni] = mfma16(qf[ks], kf, sf[ni]);
            }
        #pragma unroll
        for (int reg = 0; reg < 4; ++reg) {
            const unsigned long long mr = mrb[(size_t)(wid * 16 + hi * 4 + reg) * 32 + st] >> lo;
            const unsigned int ma = (unsigned int)mr;
            const unsigned int mbv = (unsigned int)(mr >> 32);
            const float e0 = (ma & 1u)          ? 0.f : __expf(sf[0][reg]);
            const float e1 = ((ma >> 16) & 1u)  ? 0.f : __expf(sf[1][reg]);
            const float e2 = (mbv & 1u)         ? 0.f : __expf(sf[2][reg]);
            const float e3 = ((mbv >> 16) & 1u) ? 0.f : __expf(sf[3][reg]);
            lsum[reg] += (e0 + e1) + (e2 + e3);
        }
        __syncthreads();
    }

    float il[4];
    #pragma unroll
    for (int reg = 0; reg < 4; ++reg) {
        float v = lsum[reg];
        v += __shfl_xor(v, 1);
        v += __shfl_xor(v, 2);
        v += __shfl_xor(v, 4);
        v += __shfl_xor(v, 8);
        il[reg] = 1.0f / v;
    }

    // ================= pass 1: normalized weights + PV ================
    f32x4 oacc[4];
    #pragma unroll
    for (int nd = 0; nd < 4; ++nd) oacc[nd] = zero4();

    stageK(0, 0);
    stageV(0, 0);
    __syncthreads();
    for (int st = 0; st < 32; ++st) {
        const int cur = st & 1;
        if (st < 31) { stageK(st + 1, cur ^ 1); stageV(st + 1, cur ^ 1); }

        f32x4 sf[4];
        #pragma unroll
        for (int ni = 0; ni < 4; ++ni) sf[ni] = zero4();
        #pragma unroll
        for (int ks = 0; ks < 2; ++ks)
            #pragma unroll
            for (int ni = 0; ni < 4; ++ni) {
                const int rn = ni * 16 + lo;
                const s16x8 kf = *(const s16x8*)&Ks[cur][rn * 64 + (((hi + ks * 4) ^ (rn & 7)) << 3)];
                sf[ni] = mfma16(qf[ks], kf, sf[ni]);
            }

        #pragma unroll
        for (int reg = 0; reg < 4; ++reg) {
            const int q = hi * 4 + reg;                 // q-row within wave's 16
            const unsigned long long mr = mrb[(size_t)(wid * 16 + q) * 32 + st] >> lo;
            const unsigned int ma = (unsigned int)mr;
            const unsigned int mbv = (unsigned int)(mr >> 32);
            float* wrow = Wout + (size_t)(wid * 16 + q) * 2048 + st * 64 + lo;
            #pragma unroll
            for (int ni = 0; ni < 4; ++ni) {
                const unsigned int bit =
                    (ni == 0) ? (ma & 1u) : (ni == 1) ? ((ma >> 16) & 1u)
                  : (ni == 2) ? (mbv & 1u) : ((mbv >> 16) & 1u);
                const float e = bit ? 0.f : __expf(sf[ni][reg]);
                const float wn = e * il[reg];
                __builtin_nontemporal_store(wn, wrow + ni * 16);
                const int s = lo + 16 * ni;
                Ps[wid][q * 64 + (((s >> 3) ^ (q & 7)) << 3) + (s & 7)] = f2bf(wn);
            }
        }

        // PV: oacc[nd] += P[16x64] @ V[64x(16nd..)]
        #pragma unroll
        for (int ks = 0; ks < 2; ++ks) {
            const s16x8 pf = *(const s16x8*)&Ps[wid][lo * 64 + (((ks * 4 + hi) ^ (lo & 7)) << 3)];
            #pragma unroll
            for (int nd = 0; nd < 4; ++nd) {
                const int rv = nd * 16 + lo;
                const s16x8 vf = *(const s16x8*)&Vs[cur][rv * 64 + (((hi + ks * 4) ^ (lo & 7)) << 3)];
                oacc[nd] = mfma16(pf, vf, oacc[nd]);
            }
        }
        __syncthreads();
    }

    // ---- epilogue: Oh[b*2048 + l][h*64 + d] ----
    #pragma unroll
    for (int nd = 0; nd < 4; ++nd)
        #pragma unroll
        for (int reg = 0; reg < 4; ++reg) {
            const int rl = wid * 16 + hi * 4 + reg;
            const int d = nd * 16 + lo;
            Oh[((size_t)(b * 2048 + l0 + rl) << 10) + hh * 64 + d] = f2bf(oacc[nd][reg]);
        }
}

// ---------------- launch ----------------
extern "C" void kernel_launch(void* const* d_in, const int* in_sizes, int n_in,
                              void* d_out, int out_size, void* d_ws, size_t ws_size,
                              hipStream_t stream) {
    const float* queries = (const float*)d_in[0];
    const float* keys    = (const float*)d_in[1];
    const float* values  = (const float*)d_in[2];
    const unsigned char* mask = (const unsigned char*)d_in[3];
    const float* context = (const float*)d_in[4];
    const float* Wq  = (const float*)d_in[5];  const float* bq  = (const float*)d_in[6];
    const float* Wk  = (const float*)d_in[7];  const float* bk  = (const float*)d_in[8];
    const float* Wv  = (const float*)d_in[9];  const float* bv  = (const float*)d_in[10];
    const float* Wqb = (const float*)d_in[11]; const float* bqb = (const float*)d_in[12];
    const float* Wkg = (const float*)d_in[13]; const float* bkg = (const float*)d_in[14];
    const float* Wvb = (const float*)d_in[15]; const float* bvb = (const float*)d_in[16];
    const float* Wo  = (const float*)d_in[17]; const float* bo  = (const float*)d_in[18];

    unsigned short* ws = (unsigned short*)d_ws;
    unsigned short* xq = ws + OFF_XQ;
    unsigned short* xk = ws + OFF_XK;
    unsigned short* xv = ws + OFF_XV;
    unsigned short* xc = ws + OFF_XC;
    unsigned short* wt = ws + OFF_WT;
    unsigned short* Qh = ws + OFF_QH;
    unsigned short* Kh = ws + OFF_KH;
    unsigned short* Vh = ws + OFF_VH;
    unsigned short* Oh = ws + OFF_OH;
    unsigned short* VhT = ws + OFF_XQ;                         // reuse xq after projections
    unsigned long long* mbits = (unsigned long long*)(ws + OFF_XV);  // reuse xv after V proj

    float* out0  = (float*)d_out;
    float* attnW = out0 + 4194304;

    P4 acts; acts.p[0] = queries; acts.p[1] = keys; acts.p[2] = values; acts.p[3] = context;
    cvt4<<<dim3(2048, 4), 256, 0, stream>>>(acts, xq);

    P7 wts; wts.p[0] = Wq; wts.p[1] = Wqb; wts.p[2] = Wk; wts.p[3] = Wkg;
    wts.p[4] = Wv; wts.p[5] = Wvb; wts.p[6] = Wo;
    wtr<<<dim3(32, 32, 7), 256, 0, stream>>>(wts, wt);

    // Q pre-scaled by 1/sqrt(dk)=1/8 (exact in bf16)
    proj_concat<<<dim3(8, 32), 256, 0, stream>>>(xq, xc, wt, wt + 1048576, bq, bqb, Qh, 0.125f);
    proj_concat<<<dim3(8, 32), 256, 0, stream>>>(xv, xc, wt + 4u * 1048576, wt + 5u * 1048576, bv, bvb, Vh, 1.0f);
    proj_kgate<<<dim3(8, 32), 256, 0, stream>>>(xk, xc, wt + 2u * 1048576, wt + 3u * 1048576, bk, bkg, Kh);

    vtr<<<dim3(32, 32), 256, 0, stream>>>(Vh, VhT);            // xq region now free
    mpack<<<dim3(32768), 256, 0, stream>>>(mask, mbits);       // xv region now free

    attn_fused<<<dim3(1024), 256, 0, stream>>>(Qh, Kh, VhT, mbits, attnW, Oh);

    gemm_out<<<dim3(8, 32), 256, 0, stream>>>(Oh, wt + 6u * 1048576, bo, out0);
}

// Round 4
// 379.138 us; speedup vs baseline: 1.8986x; 1.0458x over previous
//
#include <hip/hip_runtime.h>

typedef __attribute__((ext_vector_type(8))) short  s16x8;
typedef __attribute__((ext_vector_type(8))) unsigned short u16x8;
typedef __attribute__((ext_vector_type(4))) float  f32x4;

#define D_MODEL 1024
#define N_HEADS 16
#define D_HEAD  64
#define BATCH   2
#define SEQ     2048
#define M_TOK   4096   // BATCH*SEQ

// ---------------- ws layout (ushort element offsets) ----------------
#define OFF_XQ  0u            // 4M u16; reused for VhT after projections
#define OFF_XK  4194304u
#define OFF_XV  8388608u      // reused for mask bitmask after V projection
#define OFF_XC  12582912u
#define OFF_WT  16777216u     // 7 x 1048576 : Wq,Wqb,Wk,Wkg,Wv,Wvb,Wo (transposed [n][k])
#define OFF_QH  24117248u     // [B][H][T][64] bf16 (pre-scaled by 1/8)
#define OFF_KH  28311552u
#define OFF_VH  32505856u
#define OFF_OH  36700160u     // [B*T][1024] bf16

__device__ __forceinline__ unsigned short f2bf(float f) {
    unsigned int u = __builtin_bit_cast(unsigned int, f);
    u += 0x7FFFu + ((u >> 16) & 1u);
    return (unsigned short)(u >> 16);
}

__device__ __forceinline__ unsigned int pk2bf(float a, float b) {
    return (unsigned int)f2bf(a) | ((unsigned int)f2bf(b) << 16);
}

__device__ __forceinline__ void gload16(const void* g, void* l) {
    __builtin_amdgcn_global_load_lds(
        (const __attribute__((address_space(1))) unsigned int*)g,
        (__attribute__((address_space(3))) unsigned int*)l, 16, 0, 0);
}

__device__ __forceinline__ f32x4 mfma16(s16x8 a, s16x8 b, f32x4 c) {
    return __builtin_amdgcn_mfma_f32_16x16x32_bf16(a, b, c, 0, 0, 0);
}

__device__ __forceinline__ f32x4 zero4() {
    f32x4 z; z[0] = 0.f; z[1] = 0.f; z[2] = 0.f; z[3] = 0.f; return z;
}

// ---------------- conversion kernels ----------------
struct P4 { const float* p[4]; };
struct P7 { const float* p[7]; };

__global__ __launch_bounds__(256) void cvt4(P4 srcs, unsigned short* dst) {
    const int a = blockIdx.y;
    const float* s = srcs.p[a];
    unsigned short* d = dst + ((size_t)a << 22);
    const size_t i = (((size_t)blockIdx.x << 8) + threadIdx.x) << 3;
    const float4 v0 = *(const float4*)(s + i);
    const float4 v1 = *(const float4*)(s + i + 4);
    u16x8 o;
    o[0] = f2bf(v0.x); o[1] = f2bf(v0.y); o[2] = f2bf(v0.z); o[3] = f2bf(v0.w);
    o[4] = f2bf(v1.x); o[5] = f2bf(v1.y); o[6] = f2bf(v1.z); o[7] = f2bf(v1.w);
    *(u16x8*)(d + i) = o;
}

// transpose weights: Wt[n][k] = W[k][n], f32 -> bf16
__global__ __launch_bounds__(256) void wtr(P7 srcs, unsigned short* dst) {
    const int z = blockIdx.z;
    const float* W = srcs.p[z];
    unsigned short* Wt = dst + ((size_t)z << 20);
    __shared__ float T[32][33];
    const int t = threadIdx.x;
    const int r = t >> 3, c4 = (t & 7) << 2;
    const int kt = blockIdx.y << 5, nt = blockIdx.x << 5;
    const float4 v = *(const float4*)(W + ((size_t)(kt + r) << 10) + nt + c4);
    T[r][c4] = v.x; T[r][c4 + 1] = v.y; T[r][c4 + 2] = v.z; T[r][c4 + 3] = v.w;
    __syncthreads();
    ushort4 o;
    o.x = f2bf(T[c4 + 0][r]); o.y = f2bf(T[c4 + 1][r]);
    o.z = f2bf(T[c4 + 2][r]); o.w = f2bf(T[c4 + 3][r]);
    *(ushort4*)(Wt + ((size_t)(nt + r) << 10) + kt + c4) = o;
}

// V head-transpose: VhT[bh][d][s] = Vh[bh][s][d]
__global__ __launch_bounds__(256) void vtr(const unsigned short* __restrict__ Vh,
                                           unsigned short* __restrict__ VhT) {
    __shared__ unsigned short T[64][72];
    const int bh = blockIdx.y, s0 = blockIdx.x << 6;
    const unsigned short* src = Vh + ((size_t)bh * 2048 + s0) * 64;
    unsigned short* dst = VhT + (size_t)bh * 64 * 2048 + s0;
    const int t = threadIdx.x;
    const int r = t >> 3, c0 = (t & 7) << 3;
    #pragma unroll
    for (int it = 0; it < 2; ++it) {
        const int rr = it * 32 + r;
        const u16x8 v = *(const u16x8*)(src + (size_t)rr * 64 + c0);
        #pragma unroll
        for (int i = 0; i < 8; ++i) T[c0 + i][rr] = v[i];
    }
    __syncthreads();
    #pragma unroll
    for (int it = 0; it < 2; ++it) {
        const int rr = it * 32 + r;
        u16x8 o;
        #pragma unroll
        for (int i = 0; i < 8; ++i) o[i] = T[rr][c0 + i];
        *(u16x8*)(dst + (size_t)rr * 2048 + c0) = o;
    }
}

// pack mask to bits: bit i of mb[w] = mask[w*64+i] != 0. Autodetect int32 vs byte.
__global__ __launch_bounds__(256) void mpack(const unsigned char* __restrict__ maskp,
                                             unsigned long long* __restrict__ mb) {
    const unsigned int probe = ((const unsigned int*)maskp)[threadIdx.x & 63];
    const bool isInt = __all(probe <= 1u);
    const size_t i = ((size_t)blockIdx.x << 8) + threadIdx.x;
    bool v;
    if (isInt) v = ((const int*)maskp)[i] != 0;
    else       v = maskp[i] != 0;
    const unsigned long long bal = __ballot(v);
    if ((threadIdx.x & 63) == 0) mb[i >> 6] = bal;
}

// ---------------- fused projection GEMMs ----------------
// 128(M)x64(N) tile, 4 waves (2Mx2N), each wave 64x32, acc[4][2].
// grid (16, 32, 3): z selects projection. gate=0: C = A0@B0t + A1@B1t + b0+b1, *scale
//                                        gate=1: C = (A0@B0t + b0) * sigmoid(A1@B1t + b1)
struct ProjDesc {
    const unsigned short *A0, *A1, *B0, *B1;
    const float *b0, *b1;
    unsigned short* dst;
    float scale;
    int gate;
};
struct ProjArgs { ProjDesc d[3]; };

__global__ __launch_bounds__(256) void proj_all(ProjArgs pa) {
    const ProjDesc P = pa.d[blockIdx.z];
    __shared__ unsigned short Al[128 * 32];   // 8 KB
    __shared__ unsigned short Bl[64 * 32];    // 4 KB
    const int tid = threadIdx.x;
    const int wid = tid >> 6, lane = tid & 63;
    const int lo = lane & 15, hi = lane >> 4;
    const int wr = wid >> 1, wc = wid & 1;
    const int m0 = blockIdx.y << 7, n0 = blockIdx.x << 6;

    auto stage = [&](const unsigned short* As, const unsigned short* Bs, int k0) {
        #pragma unroll
        for (int it = 0; it < 2; ++it) {
            const int c = it * 256 + tid;
            const int r = c >> 2, j = c & 3;
            gload16(As + ((size_t)(m0 + r) << 10) + k0 + j * 8, Al + c * 8);
        }
        const int rb = tid >> 2, jb = tid & 3;
        gload16(Bs + ((size_t)(n0 + rb) << 10) + k0 + jb * 8, Bl + tid * 8);
    };
    auto compute = [&](f32x4 (&acc)[4][2]) {
        s16x8 af[4], bfr[2];
        #pragma unroll
        for (int mi = 0; mi < 4; ++mi)
            af[mi] = *(const s16x8*)&Al[(wr * 64 + mi * 16 + lo) * 32 + hi * 8];
        #pragma unroll
        for (int ni = 0; ni < 2; ++ni)
            bfr[ni] = *(const s16x8*)&Bl[(wc * 32 + ni * 16 + lo) * 32 + hi * 8];
        __builtin_amdgcn_s_setprio(1);
        #pragma unroll
        for (int mi = 0; mi < 4; ++mi)
            #pragma unroll
            for (int ni = 0; ni < 2; ++ni)
                acc[mi][ni] = mfma16(af[mi], bfr[ni], acc[mi][ni]);
        __builtin_amdgcn_s_setprio(0);
    };

    if (P.gate) {
        f32x4 acc0[4][2], acc1[4][2];
        #pragma unroll
        for (int i = 0; i < 4; ++i)
            #pragma unroll
            for (int j = 0; j < 2; ++j) { acc0[i][j] = zero4(); acc1[i][j] = zero4(); }
        for (int kt = 0; kt < 32; ++kt) {
            __syncthreads();
            stage(P.A0, P.B0, kt << 5);
            __syncthreads();
            compute(acc0);
        }
        for (int kt = 0; kt < 32; ++kt) {
            __syncthreads();
            stage(P.A1, P.B1, kt << 5);
            __syncthreads();
            compute(acc1);
        }
        #pragma unroll
        for (int mi = 0; mi < 4; ++mi)
            #pragma unroll
            for (int ni = 0; ni < 2; ++ni) {
                const int n = n0 + wc * 32 + ni * 16 + lo;
                const float b0 = P.b0[n], b1 = P.b1[n];
                const int h = n >> 6, d = n & 63;
                #pragma unroll
                for (int reg = 0; reg < 4; ++reg) {
                    const int m = m0 + wr * 64 + mi * 16 + hi * 4 + reg;
                    const int b = m >> 11, t = m & 2047;
                    const float kv = acc0[mi][ni][reg] + b0;
                    const float gv = acc1[mi][ni][reg] + b1;
                    const float sg = 1.0f / (1.0f + __expf(-gv));
                    P.dst[((size_t)((b * 16 + h) * 2048 + t) << 6) + d] = f2bf(kv * sg);
                }
            }
    } else {
        f32x4 acc[4][2];
        #pragma unroll
        for (int i = 0; i < 4; ++i)
            #pragma unroll
            for (int j = 0; j < 2; ++j) acc[i][j] = zero4();
        for (int kt = 0; kt < 64; ++kt) {
            const unsigned short* As = (kt < 32) ? P.A0 : P.A1;
            const unsigned short* Bs = (kt < 32) ? P.B0 : P.B1;
            __syncthreads();
            stage(As, Bs, (kt & 31) << 5);
            __syncthreads();
            compute(acc);
        }
        #pragma unroll
        for (int mi = 0; mi < 4; ++mi)
            #pragma unroll
            for (int ni = 0; ni < 2; ++ni) {
                const int n = n0 + wc * 32 + ni * 16 + lo;
                const float bsum = P.b0[n] + P.b1[n];
                const int h = n >> 6, d = n & 63;
                #pragma unroll
                for (int reg = 0; reg < 4; ++reg) {
                    const int m = m0 + wr * 64 + mi * 16 + hi * 4 + reg;
                    const int b = m >> 11, t = m & 2047;
                    P.dst[((size_t)((b * 16 + h) * 2048 + t) << 6) + d] =
                        f2bf((acc[mi][ni][reg] + bsum) * P.scale);
                }
            }
    }
}

// out0 = Oh @ Wo + bo  (f32 output), 128x64 tile
__global__ __launch_bounds__(256) void gemm_out(
    const unsigned short* __restrict__ A, const unsigned short* __restrict__ Bt,
    const float* __restrict__ bias, float* __restrict__ out)
{
    __shared__ unsigned short Al[128 * 32];
    __shared__ unsigned short Bl[64 * 32];
    const int tid = threadIdx.x;
    const int wid = tid >> 6, lane = tid & 63;
    const int lo = lane & 15, hi = lane >> 4;
    const int wr = wid >> 1, wc = wid & 1;
    const int m0 = blockIdx.y << 7, n0 = blockIdx.x << 6;

    f32x4 acc[4][2];
    #pragma unroll
    for (int i = 0; i < 4; ++i)
        #pragma unroll
        for (int j = 0; j < 2; ++j) acc[i][j] = zero4();

    for (int kt = 0; kt < 32; ++kt) {
        const int k0 = kt << 5;
        __syncthreads();
        #pragma unroll
        for (int it = 0; it < 2; ++it) {
            const int c = it * 256 + tid;
            const int r = c >> 2, j = c & 3;
            gload16(A + ((size_t)(m0 + r) << 10) + k0 + j * 8, Al + c * 8);
        }
        {
            const int rb = tid >> 2, jb = tid & 3;
            gload16(Bt + ((size_t)(n0 + rb) << 10) + k0 + jb * 8, Bl + tid * 8);
        }
        __syncthreads();
        s16x8 af[4], bfr[2];
        #pragma unroll
        for (int mi = 0; mi < 4; ++mi)
            af[mi] = *(const s16x8*)&Al[(wr * 64 + mi * 16 + lo) * 32 + hi * 8];
        #pragma unroll
        for (int ni = 0; ni < 2; ++ni)
            bfr[ni] = *(const s16x8*)&Bl[(wc * 32 + ni * 16 + lo) * 32 + hi * 8];
        __builtin_amdgcn_s_setprio(1);
        #pragma unroll
        for (int mi = 0; mi < 4; ++mi)
            #pragma unroll
            for (int ni = 0; ni < 2; ++ni)
                acc[mi][ni] = mfma16(af[mi], bfr[ni], acc[mi][ni]);
        __builtin_amdgcn_s_setprio(0);
    }

    #pragma unroll
    for (int mi = 0; mi < 4; ++mi)
        #pragma unroll
        for (int ni = 0; ni < 2; ++ni) {
            const int n = n0 + wc * 32 + ni * 16 + lo;
            const float bb = bias[n];
            #pragma unroll
            for (int reg = 0; reg < 4; ++reg) {
                const int m = m0 + wr * 64 + mi * 16 + hi * 4 + reg;
                out[((size_t)m << 10) + n] = acc[mi][ni][reg] + bb;
            }
        }
}

// ---------------- fused attention (swapped-QK layout) ----------------
// 1024 blocks (XCD-chunked), 256 threads, 4 waves; Q-tile 64 rows (16/wave).
// S^T = mfma(K, Q): lane owns q = wid*16 + (lane&15); per n-block 4 consecutive s.
// attnW stores: 4x f32x4 nontemporal per tile per thread.
__global__ __launch_bounds__(256, 4) void attn_fused(
    const unsigned short* __restrict__ Qh, const unsigned short* __restrict__ Kh,
    const unsigned short* __restrict__ VhT, const unsigned long long* __restrict__ mbits,
    float* __restrict__ attnW, unsigned short* __restrict__ Oh)
{
    __shared__ unsigned short Ks[2][4096];   // [64 s][64 d], 16B chunks XOR-swizzled by row&7
    __shared__ unsigned short Vs[2][4096];   // [64 d][64 s], same swizzle
    __shared__ unsigned short Ps[4][1024];   // per-wave P^T-ish [16 q][64 s], 16B chunk ^= (q&7)<<4

    const int tid = threadIdx.x;
    const int wid = tid >> 6, lane = tid & 63;
    const int lo = lane & 15, hi = lane >> 4;

    const int wg = blockIdx.x;
    const int gid = (wg & 7) * 128 + (wg >> 3);
    const int bh = gid >> 5, lt = gid & 31;
    const int b = bh >> 4, hh = bh & 15;
    const int l0 = lt << 6;

    const unsigned short* Qp = Qh + ((size_t)bh * 2048 + l0) * 64;
    const unsigned short* Kp = Kh + (size_t)bh * 2048 * 64;
    const unsigned short* Vp = VhT + (size_t)bh * 64 * 2048;

    const int q = wid * 16 + lo;   // this thread's q row
    float* Wrow = attnW + ((size_t)bh * 2048 + l0 + q) * 2048 + hi * 4;
    const unsigned long long* mq = mbits + ((size_t)b * 2048 + l0 + q) * 32;

    // Q fragment (B-operand): rows q, pre-scaled by 1/8 at projection
    s16x8 qf[2];
    {
        const unsigned short* qr = Qp + (size_t)q * 64 + hi * 8;
        qf[0] = *(const s16x8*)qr;
        qf[1] = *(const s16x8*)(qr + 32);
    }

    auto stageK = [&](int st, int bufi) {
        const unsigned short* src = Kp + (size_t)(st << 6) * 64;
        #pragma unroll
        for (int it = 0; it < 2; ++it) {
            const int c = it * 256 + tid;
            const int r = c >> 3, j = c & 7;
            gload16(src + (size_t)r * 64 + ((j ^ (r & 7)) << 3), &Ks[bufi][c * 8]);
        }
    };
    auto stageV = [&](int st, int bufi) {
        const unsigned short* src = Vp + (st << 6);
        #pragma unroll
        for (int it = 0; it < 2; ++it) {
            const int c = it * 256 + tid;
            const int r = c >> 3, j = c & 7;
            gload16(src + (size_t)r * 2048 + ((j ^ (r & 7)) << 3), &Vs[bufi][c * 8]);
        }
    };

    // ================= pass 0: row sums of exp(s) ====
    float lsum = 0.f;
    stageK(0, 0);
    __syncthreads();
    for (int st = 0; st < 32; ++st) {
        const int cur = st & 1;
        if (st < 31) stageK(st + 1, cur ^ 1);

        const unsigned long long mrow = mq[st] >> (hi * 4);
        f32x4 sf[4];
        #pragma unroll
        for (int ni = 0; ni < 4; ++ni) sf[ni] = zero4();
        __builtin_amdgcn_s_setprio(1);
        #pragma unroll
        for (int ks = 0; ks < 2; ++ks)
            #pragma unroll
            for (int ni = 0; ni < 4; ++ni) {
                const int rn = ni * 16 + lo;
                const s16x8 kf = *(const s16x8*)&Ks[cur][rn * 64 + (((hi + ks * 4) ^ (rn & 7)) << 3)];
                sf[ni] = mfma16(kf, qf[ks], sf[ni]);   // S^T: row=s, col=q
            }
        __builtin_amdgcn_s_setprio(0);
        #pragma unroll
        for (int ni = 0; ni < 4; ++ni)
            #pragma unroll
            for (int reg = 0; reg < 4; ++reg) {
                const unsigned int bit = (unsigned int)(mrow >> (ni * 16 + reg)) & 1u;
                lsum += bit ? 0.f : __expf(sf[ni][reg]);
            }
        __syncthreads();
    }
    lsum += __shfl_xor(lsum, 16);
    lsum += __shfl_xor(lsum, 32);
    const float il = 1.0f / lsum;

    // ================= pass 1: normalized weights + PV ================
    f32x4 oacc[4];
    #pragma unroll
    for (int nd = 0; nd < 4; ++nd) oacc[nd] = zero4();

    stageK(0, 0);
    stageV(0, 0);
    __syncthreads();
    for (int st = 0; st < 32; ++st) {
        const int cur = st & 1;
        if (st < 31) { stageK(st + 1, cur ^ 1); stageV(st + 1, cur ^ 1); }

        const unsigned long long mrow = mq[st] >> (hi * 4);
        f32x4 sf[4];
        #pragma unroll
        for (int ni = 0; ni < 4; ++ni) sf[ni] = zero4();
        __builtin_amdgcn_s_setprio(1);
        #pragma unroll
        for (int ks = 0; ks < 2; ++ks)
            #pragma unroll
            for (int ni = 0; ni < 4; ++ni) {
                const int rn = ni * 16 + lo;
                const s16x8 kf = *(const s16x8*)&Ks[cur][rn * 64 + (((hi + ks * 4) ^ (rn & 7)) << 3)];
                sf[ni] = mfma16(kf, qf[ks], sf[ni]);
            }
        __builtin_amdgcn_s_setprio(0);

        #pragma unroll
        for (int ni = 0; ni < 4; ++ni) {
            f32x4 wv;
            #pragma unroll
            for (int reg = 0; reg < 4; ++reg) {
                const unsigned int bit = (unsigned int)(mrow >> (ni * 16 + reg)) & 1u;
                const float e = bit ? 0.f : __expf(sf[ni][reg]);
                wv[reg] = e * il;
            }
            __builtin_nontemporal_store(wv, (f32x4*)(Wrow + (size_t)st * 64 + ni * 16));
            const unsigned int p01 = pk2bf(wv[0], wv[1]);
            const unsigned int p23 = pk2bf(wv[2], wv[3]);
            *(uint2*)((char*)&Ps[wid][0] + lo * 128 + ((ni * 32 + hi * 8) ^ ((lo & 7) << 4))) =
                make_uint2(p01, p23);
        }

        // PV: O[q][d] += P[q][s] V[s][d]
        __builtin_amdgcn_s_setprio(1);
        #pragma unroll
        for (int ks = 0; ks < 2; ++ks) {
            const s16x8 pf = *(const s16x8*)((const char*)&Ps[wid][0] +
                lo * 128 + ((ks * 64 + hi * 16) ^ ((lo & 7) << 4)));
            #pragma unroll
            for (int nd = 0; nd < 4; ++nd) {
                const int rv = nd * 16 + lo;
                const s16x8 vf = *(const s16x8*)&Vs[cur][rv * 64 + (((hi + ks * 4) ^ (rv & 7)) << 3)];
                oacc[nd] = mfma16(pf, vf, oacc[nd]);
            }
        }
        __builtin_amdgcn_s_setprio(0);
        __syncthreads();
    }

    // ---- epilogue: Oh[b*2048 + l][h*64 + d] ----
    #pragma unroll
    for (int nd = 0; nd < 4; ++nd)
        #pragma unroll
        for (int reg = 0; reg < 4; ++reg) {
            const int rl = wid * 16 + hi * 4 + reg;
            const int d = nd * 16 + lo;
            Oh[((size_t)(b * 2048 + l0 + rl) << 10) + hh * 64 + d] = f2bf(oacc[nd][reg]);
        }
}

// ---------------- launch ----------------
extern "C" void kernel_launch(void* const* d_in, const int* in_sizes, int n_in,
                              void* d_out, int out_size, void* d_ws, size_t ws_size,
                              hipStream_t stream) {
    const float* queries = (const float*)d_in[0];
    const float* keys    = (const float*)d_in[1];
    const float* values  = (const float*)d_in[2];
    const unsigned char* mask = (const unsigned char*)d_in[3];
    const float* context = (const float*)d_in[4];
    const float* Wq  = (const float*)d_in[5];  const float* bq  = (const float*)d_in[6];
    const float* Wk  = (const float*)d_in[7];  const float* bk  = (const float*)d_in[8];
    const float* Wv  = (const float*)d_in[9];  const float* bv  = (const float*)d_in[10];
    const float* Wqb = (const float*)d_in[11]; const float* bqb = (const float*)d_in[12];
    const float* Wkg = (const float*)d_in[13]; const float* bkg = (const float*)d_in[14];
    const float* Wvb = (const float*)d_in[15]; const float* bvb = (const float*)d_in[16];
    const float* Wo  = (const float*)d_in[17]; const float* bo  = (const float*)d_in[18];

    unsigned short* ws = (unsigned short*)d_ws;
    unsigned short* xq = ws + OFF_XQ;
    unsigned short* xk = ws + OFF_XK;
    unsigned short* xv = ws + OFF_XV;
    unsigned short* xc = ws + OFF_XC;
    unsigned short* wt = ws + OFF_WT;
    unsigned short* Qh = ws + OFF_QH;
    unsigned short* Kh = ws + OFF_KH;
    unsigned short* Vh = ws + OFF_VH;
    unsigned short* Oh = ws + OFF_OH;
    unsigned short* VhT = ws + OFF_XQ;                               // reuse xq after projections
    unsigned long long* mbits = (unsigned long long*)(ws + OFF_XV);  // reuse xv after V proj

    float* out0  = (float*)d_out;
    float* attnW = out0 + 4194304;

    P4 acts; acts.p[0] = queries; acts.p[1] = keys; acts.p[2] = values; acts.p[3] = context;
    cvt4<<<dim3(2048, 4), 256, 0, stream>>>(acts, xq);

    P7 wts; wts.p[0] = Wq; wts.p[1] = Wqb; wts.p[2] = Wk; wts.p[3] = Wkg;
    wts.p[4] = Wv; wts.p[5] = Wvb; wts.p[6] = Wo;
    wtr<<<dim3(32, 32, 7), 256, 0, stream>>>(wts, wt);

    ProjArgs pa;
    // z=0: Qh = ([Xq|Xc] @ [Wq;Wqb] + bq + bqb) * 0.125   (1/sqrt(dk) folded)
    pa.d[0] = { xq, xc, wt, wt + 1048576u, bq, bqb, Qh, 0.125f, 0 };
    // z=1: Vh = [Xv|Xc] @ [Wv;Wvb] + bv + bvb
    pa.d[1] = { xv, xc, wt + 4u * 1048576u, wt + 5u * 1048576u, bv, bvb, Vh, 1.0f, 0 };
    // z=2: Kh = (Xk@Wk + bk) * sigmoid(Xc@Wkg + bkg)
    pa.d[2] = { xk, xc, wt + 2u * 1048576u, wt + 3u * 1048576u, bk, bkg, Kh, 1.0f, 1 };
    proj_all<<<dim3(16, 32, 3), 256, 0, stream>>>(pa);

    vtr<<<dim3(32, 32), 256, 0, stream>>>(Vh, VhT);            // xq region now free
    mpack<<<dim3(32768), 256, 0, stream>>>(mask, mbits);       // xv region now free

    attn_fused<<<dim3(1024), 256, 0, stream>>>(Qh, Kh, VhT, mbits, attnW, Oh);

    gemm_out<<<dim3(16, 32), 256, 0, stream>>>(Oh, wt + 6u * 1048576u, bo, out0);
}

// Round 5
// 372.922 us; speedup vs baseline: 1.9303x; 1.0167x over previous
//
#include <hip/hip_runtime.h>

typedef __attribute__((ext_vector_type(8))) short  s16x8;
typedef __attribute__((ext_vector_type(8))) unsigned short u16x8;
typedef __attribute__((ext_vector_type(4))) float  f32x4;

#define D_MODEL 1024
#define N_HEADS 16
#define D_HEAD  64
#define BATCH   2
#define SEQ     2048
#define M_TOK   4096   // BATCH*SEQ

// ---------------- ws layout (ushort element offsets) ----------------
#define OFF_XQ  0u            // 4M u16; reused for VhT after projections
#define OFF_XK  4194304u
#define OFF_XV  8388608u      // reused for mask bitmask after V projection
#define OFF_XC  12582912u
#define OFF_WT  16777216u     // 7 x 1048576 : Wq,Wqb,Wk,Wkg,Wv,Wvb,Wo (transposed [n][k])
#define OFF_QH  24117248u     // [B][H][T][64] bf16 (pre-scaled by log2e/8)
#define OFF_KH  28311552u
#define OFF_VH  32505856u
#define OFF_OH  36700160u     // [B*T][1024] bf16

__device__ __forceinline__ unsigned short f2bf(float f) {
    unsigned int u = __builtin_bit_cast(unsigned int, f);
    u += 0x7FFFu + ((u >> 16) & 1u);
    return (unsigned short)(u >> 16);
}

// single-instruction packed f32x2 -> bf16x2 (RNE), replaces ~9 VALU ops
__device__ __forceinline__ unsigned int cvtpk(float a, float b) {
    unsigned int r;
    asm("v_cvt_pk_bf16_f32 %0, %1, %2" : "=v"(r) : "v"(a), "v"(b));
    return r;
}

__device__ __forceinline__ void gload16(const void* g, void* l) {
    __builtin_amdgcn_global_load_lds(
        (const __attribute__((address_space(1))) unsigned int*)g,
        (__attribute__((address_space(3))) unsigned int*)l, 16, 0, 0);
}

__device__ __forceinline__ f32x4 mfma16(s16x8 a, s16x8 b, f32x4 c) {
    return __builtin_amdgcn_mfma_f32_16x16x32_bf16(a, b, c, 0, 0, 0);
}

__device__ __forceinline__ f32x4 zero4() {
    f32x4 z; z[0] = 0.f; z[1] = 0.f; z[2] = 0.f; z[3] = 0.f; return z;
}

// ---------------- conversion kernels ----------------
struct P4 { const float* p[4]; };
struct P7 { const float* p[7]; };

__global__ __launch_bounds__(256) void cvt4(P4 srcs, unsigned short* dst) {
    const int a = blockIdx.y;
    const float* s = srcs.p[a];
    unsigned short* d = dst + ((size_t)a << 22);
    const size_t i = (((size_t)blockIdx.x << 8) + threadIdx.x) << 3;
    const float4 v0 = *(const float4*)(s + i);
    const float4 v1 = *(const float4*)(s + i + 4);
    u16x8 o;
    o[0] = f2bf(v0.x); o[1] = f2bf(v0.y); o[2] = f2bf(v0.z); o[3] = f2bf(v0.w);
    o[4] = f2bf(v1.x); o[5] = f2bf(v1.y); o[6] = f2bf(v1.z); o[7] = f2bf(v1.w);
    *(u16x8*)(d + i) = o;
}

// transpose weights: Wt[n][k] = W[k][n], f32 -> bf16
__global__ __launch_bounds__(256) void wtr(P7 srcs, unsigned short* dst) {
    const int z = blockIdx.z;
    const float* W = srcs.p[z];
    unsigned short* Wt = dst + ((size_t)z << 20);
    __shared__ float T[32][33];
    const int t = threadIdx.x;
    const int r = t >> 3, c4 = (t & 7) << 2;
    const int kt = blockIdx.y << 5, nt = blockIdx.x << 5;
    const float4 v = *(const float4*)(W + ((size_t)(kt + r) << 10) + nt + c4);
    T[r][c4] = v.x; T[r][c4 + 1] = v.y; T[r][c4 + 2] = v.z; T[r][c4 + 3] = v.w;
    __syncthreads();
    ushort4 o;
    o.x = f2bf(T[c4 + 0][r]); o.y = f2bf(T[c4 + 1][r]);
    o.z = f2bf(T[c4 + 2][r]); o.w = f2bf(T[c4 + 3][r]);
    *(ushort4*)(Wt + ((size_t)(nt + r) << 10) + kt + c4) = o;
}

// V head-transpose: VhT[bh][d][s] = Vh[bh][s][d]
__global__ __launch_bounds__(256) void vtr(const unsigned short* __restrict__ Vh,
                                           unsigned short* __restrict__ VhT) {
    __shared__ unsigned short T[64][72];
    const int bh = blockIdx.y, s0 = blockIdx.x << 6;
    const unsigned short* src = Vh + ((size_t)bh * 2048 + s0) * 64;
    unsigned short* dst = VhT + (size_t)bh * 64 * 2048 + s0;
    const int t = threadIdx.x;
    const int r = t >> 3, c0 = (t & 7) << 3;
    #pragma unroll
    for (int it = 0; it < 2; ++it) {
        const int rr = it * 32 + r;
        const u16x8 v = *(const u16x8*)(src + (size_t)rr * 64 + c0);
        #pragma unroll
        for (int i = 0; i < 8; ++i) T[c0 + i][rr] = v[i];
    }
    __syncthreads();
    #pragma unroll
    for (int it = 0; it < 2; ++it) {
        const int rr = it * 32 + r;
        u16x8 o;
        #pragma unroll
        for (int i = 0; i < 8; ++i) o[i] = T[rr][c0 + i];
        *(u16x8*)(dst + (size_t)rr * 2048 + c0) = o;
    }
}

// pack mask to bits: bit i of mb[w] = mask[w*64+i] != 0. Autodetect int32 vs byte.
__global__ __launch_bounds__(256) void mpack(const unsigned char* __restrict__ maskp,
                                             unsigned long long* __restrict__ mb) {
    const unsigned int probe = ((const unsigned int*)maskp)[threadIdx.x & 63];
    const bool isInt = __all(probe <= 1u);
    const size_t i = ((size_t)blockIdx.x << 8) + threadIdx.x;
    bool v;
    if (isInt) v = ((const int*)maskp)[i] != 0;
    else       v = maskp[i] != 0;
    const unsigned long long bal = __ballot(v);
    if ((threadIdx.x & 63) == 0) mb[i >> 6] = bal;
}

// ---------------- fused projection GEMMs (2-phase double-buffered) ----------------
// 128(M)x64(N) tile, 4 waves (2Mx2N), 64 K-steps: t<32 -> A0/B0 into acc0, t>=32 -> A1/B1 into acc1.
// gate=0: C = (acc0+acc1 + b0+b1) * scale ; gate=1: C = (acc0+b0) * sigmoid(acc1+b1)
struct ProjDesc {
    const unsigned short *A0, *A1, *B0, *B1;
    const float *b0, *b1;
    unsigned short* dst;
    float scale;
    int gate;
};
struct ProjArgs { ProjDesc d[3]; };

__global__ __launch_bounds__(256) void proj_all(ProjArgs pa) {
    const ProjDesc P = pa.d[blockIdx.z];
    __shared__ unsigned short Al[2][128 * 32];   // 2 x 8 KB
    __shared__ unsigned short Bl[2][64 * 32];    // 2 x 4 KB
    const int tid = threadIdx.x;
    const int wid = tid >> 6, lane = tid & 63;
    const int lo = lane & 15, hi = lane >> 4;
    const int wr = wid >> 1, wc = wid & 1;
    const int m0 = blockIdx.y << 7, n0 = blockIdx.x << 6;

    auto stageT = [&](int t) {
        const int bufi = t & 1;
        const unsigned short* As = (t < 32) ? P.A0 : P.A1;
        const unsigned short* Bs = (t < 32) ? P.B0 : P.B1;
        const int k0 = (t & 31) << 5;
        #pragma unroll
        for (int it = 0; it < 2; ++it) {
            const int c = it * 256 + tid;
            const int r = c >> 2, j = c & 3;
            gload16(As + ((size_t)(m0 + r) << 10) + k0 + j * 8, &Al[bufi][c * 8]);
        }
        const int rb = tid >> 2, jb = tid & 3;
        gload16(Bs + ((size_t)(n0 + rb) << 10) + k0 + jb * 8, &Bl[bufi][tid * 8]);
    };

    f32x4 acc0[4][2], acc1[4][2];
    #pragma unroll
    for (int i = 0; i < 4; ++i)
        #pragma unroll
        for (int j = 0; j < 2; ++j) { acc0[i][j] = zero4(); acc1[i][j] = zero4(); }

    stageT(0);
    for (int t = 0; t < 64; ++t) {
        __syncthreads();            // drains stage(t); protects buf being overwritten
        if (t < 63) stageT(t + 1);  // in flight across compute(t)
        const int bufi = t & 1;
        s16x8 af[4], bfr[2];
        #pragma unroll
        for (int mi = 0; mi < 4; ++mi)
            af[mi] = *(const s16x8*)&Al[bufi][(wr * 64 + mi * 16 + lo) * 32 + hi * 8];
        #pragma unroll
        for (int ni = 0; ni < 2; ++ni)
            bfr[ni] = *(const s16x8*)&Bl[bufi][(wc * 32 + ni * 16 + lo) * 32 + hi * 8];
        __builtin_amdgcn_s_setprio(1);
        if (t < 32) {
            #pragma unroll
            for (int mi = 0; mi < 4; ++mi)
                #pragma unroll
                for (int ni = 0; ni < 2; ++ni)
                    acc0[mi][ni] = mfma16(af[mi], bfr[ni], acc0[mi][ni]);
        } else {
            #pragma unroll
            for (int mi = 0; mi < 4; ++mi)
                #pragma unroll
                for (int ni = 0; ni < 2; ++ni)
                    acc1[mi][ni] = mfma16(af[mi], bfr[ni], acc1[mi][ni]);
        }
        __builtin_amdgcn_s_setprio(0);
    }

    #pragma unroll
    for (int mi = 0; mi < 4; ++mi)
        #pragma unroll
        for (int ni = 0; ni < 2; ++ni) {
            const int n = n0 + wc * 32 + ni * 16 + lo;
            const float b0 = P.b0[n], b1 = P.b1[n];
            const int h = n >> 6, d = n & 63;
            #pragma unroll
            for (int reg = 0; reg < 4; ++reg) {
                const int m = m0 + wr * 64 + mi * 16 + hi * 4 + reg;
                const int b = m >> 11, t = m & 2047;
                float val;
                if (P.gate) {
                    const float kv = acc0[mi][ni][reg] + b0;
                    const float gv = acc1[mi][ni][reg] + b1;
                    val = kv * (1.0f / (1.0f + __expf(-gv)));
                } else {
                    val = (acc0[mi][ni][reg] + acc1[mi][ni][reg] + b0 + b1) * P.scale;
                }
                P.dst[((size_t)((b * 16 + h) * 2048 + t) << 6) + d] = f2bf(val);
            }
        }
}

// out0 = Oh @ Wo + bo  (f32 output), 128x64 tile, 2-phase double-buffered
__global__ __launch_bounds__(256) void gemm_out(
    const unsigned short* __restrict__ A, const unsigned short* __restrict__ Bt,
    const float* __restrict__ bias, float* __restrict__ out)
{
    __shared__ unsigned short Al[2][128 * 32];
    __shared__ unsigned short Bl[2][64 * 32];
    const int tid = threadIdx.x;
    const int wid = tid >> 6, lane = tid & 63;
    const int lo = lane & 15, hi = lane >> 4;
    const int wr = wid >> 1, wc = wid & 1;
    const int m0 = blockIdx.y << 7, n0 = blockIdx.x << 6;

    auto stageT = [&](int t) {
        const int bufi = t & 1;
        const int k0 = t << 5;
        #pragma unroll
        for (int it = 0; it < 2; ++it) {
            const int c = it * 256 + tid;
            const int r = c >> 2, j = c & 3;
            gload16(A + ((size_t)(m0 + r) << 10) + k0 + j * 8, &Al[bufi][c * 8]);
        }
        const int rb = tid >> 2, jb = tid & 3;
        gload16(Bt + ((size_t)(n0 + rb) << 10) + k0 + jb * 8, &Bl[bufi][tid * 8]);
    };

    f32x4 acc[4][2];
    #pragma unroll
    for (int i = 0; i < 4; ++i)
        #pragma unroll
        for (int j = 0; j < 2; ++j) acc[i][j] = zero4();

    stageT(0);
    for (int t = 0; t < 32; ++t) {
        __syncthreads();
        if (t < 31) stageT(t + 1);
        const int bufi = t & 1;
        s16x8 af[4], bfr[2];
        #pragma unroll
        for (int mi = 0; mi < 4; ++mi)
            af[mi] = *(const s16x8*)&Al[bufi][(wr * 64 + mi * 16 + lo) * 32 + hi * 8];
        #pragma unroll
        for (int ni = 0; ni < 2; ++ni)
            bfr[ni] = *(const s16x8*)&Bl[bufi][(wc * 32 + ni * 16 + lo) * 32 + hi * 8];
        __builtin_amdgcn_s_setprio(1);
        #pragma unroll
        for (int mi = 0; mi < 4; ++mi)
            #pragma unroll
            for (int ni = 0; ni < 2; ++ni)
                acc[mi][ni] = mfma16(af[mi], bfr[ni], acc[mi][ni]);
        __builtin_amdgcn_s_setprio(0);
    }

    #pragma unroll
    for (int mi = 0; mi < 4; ++mi)
        #pragma unroll
        for (int ni = 0; ni < 2; ++ni) {
            const int n = n0 + wc * 32 + ni * 16 + lo;
            const float bb = bias[n];
            #pragma unroll
            for (int reg = 0; reg < 4; ++reg) {
                const int m = m0 + wr * 64 + mi * 16 + hi * 4 + reg;
                out[((size_t)m << 10) + n] = acc[mi][ni][reg] + bb;
            }
        }
}

// ---------------- fused attention (swapped-QK layout, base-2 softmax) ----------------
// Q pre-scaled by log2e/8 at projection -> scores are base-2 exponents; exp2f = 1 inst.
// 1024 blocks (XCD-chunked), 256 threads, 4 waves; Q-tile 64 rows (16/wave).
// S^T = mfma(K, Q): lane owns q = wid*16 + (lane&15); per n-block 4 consecutive s.
__global__ __launch_bounds__(256, 4) void attn_fused(
    const unsigned short* __restrict__ Qh, const unsigned short* __restrict__ Kh,
    const unsigned short* __restrict__ VhT, const unsigned long long* __restrict__ mbits,
    float* __restrict__ attnW, unsigned short* __restrict__ Oh)
{
    __shared__ unsigned short Ks[2][4096];   // [64 s][64 d], 16B chunks XOR-swizzled by row&7
    __shared__ unsigned short Vs[2][4096];   // [64 d][64 s], same swizzle
    __shared__ unsigned short Ps[4][1024];   // per-wave P^T [16 q][64 s], 16B chunk ^= (q&7)<<4

    const int tid = threadIdx.x;
    const int wid = tid >> 6, lane = tid & 63;
    const int lo = lane & 15, hi = lane >> 4;

    const int wg = blockIdx.x;
    const int gid = (wg & 7) * 128 + (wg >> 3);
    const int bh = gid >> 5, lt = gid & 31;
    const int b = bh >> 4, hh = bh & 15;
    const int l0 = lt << 6;

    const unsigned short* Qp = Qh + ((size_t)bh * 2048 + l0) * 64;
    const unsigned short* Kp = Kh + (size_t)bh * 2048 * 64;
    const unsigned short* Vp = VhT + (size_t)bh * 64 * 2048;

    const int q = wid * 16 + lo;   // this thread's q row
    float* Wrow = attnW + ((size_t)bh * 2048 + l0 + q) * 2048 + hi * 4;
    const unsigned long long* mq = mbits + ((size_t)b * 2048 + l0 + q) * 32;

    // Q fragment (B-operand): rows q, pre-scaled by log2e/8 at projection
    s16x8 qf[2];
    {
        const unsigned short* qr = Qp + (size_t)q * 64 + hi * 8;
        qf[0] = *(const s16x8*)qr;
        qf[1] = *(const s16x8*)(qr + 32);
    }

    auto stageK = [&](int st, int bufi) {
        const unsigned short* src = Kp + (size_t)(st << 6) * 64;
        #pragma unroll
        for (int it = 0; it < 2; ++it) {
            const int c = it * 256 + tid;
            const int r = c >> 3, j = c & 7;
            gload16(src + (size_t)r * 64 + ((j ^ (r & 7)) << 3), &Ks[bufi][c * 8]);
        }
    };
    auto stageV = [&](int st, int bufi) {
        const unsigned short* src = Vp + (st << 6);
        #pragma unroll
        for (int it = 0; it < 2; ++it) {
            const int c = it * 256 + tid;
            const int r = c >> 3, j = c & 7;
            gload16(src + (size_t)r * 2048 + ((j ^ (r & 7)) << 3), &Vs[bufi][c * 8]);
        }
    };

    // ================= pass 0: row sums of 2^s ====
    float lsum = 0.f;
    stageK(0, 0);
    __syncthreads();
    for (int st = 0; st < 32; ++st) {
        const int cur = st & 1;
        if (st < 31) stageK(st + 1, cur ^ 1);

        const unsigned long long mrow = mq[st] >> (hi * 4);
        f32x4 sf[4];
        #pragma unroll
        for (int ni = 0; ni < 4; ++ni) sf[ni] = zero4();
        __builtin_amdgcn_s_setprio(1);
        #pragma unroll
        for (int ks = 0; ks < 2; ++ks)
            #pragma unroll
            for (int ni = 0; ni < 4; ++ni) {
                const int rn = ni * 16 + lo;
                const s16x8 kf = *(const s16x8*)&Ks[cur][rn * 64 + (((hi + ks * 4) ^ (rn & 7)) << 3)];
                sf[ni] = mfma16(kf, qf[ks], sf[ni]);   // S^T: row=s, col=q
            }
        __builtin_amdgcn_s_setprio(0);
        #pragma unroll
        for (int ni = 0; ni < 4; ++ni)
            #pragma unroll
            for (int reg = 0; reg < 4; ++reg) {
                const unsigned int bit = (unsigned int)(mrow >> (ni * 16 + reg)) & 1u;
                lsum += bit ? 0.f : exp2f(sf[ni][reg]);
            }
        __syncthreads();
    }
    lsum += __shfl_xor(lsum, 16);
    lsum += __shfl_xor(lsum, 32);
    const float il = 1.0f / lsum;

    // ================= pass 1: normalized weights + PV ================
    f32x4 oacc[4];
    #pragma unroll
    for (int nd = 0; nd < 4; ++nd) oacc[nd] = zero4();

    stageK(0, 0);
    stageV(0, 0);
    __syncthreads();
    for (int st = 0; st < 32; ++st) {
        const int cur = st & 1;
        if (st < 31) { stageK(st + 1, cur ^ 1); stageV(st + 1, cur ^ 1); }

        const unsigned long long mrow = mq[st] >> (hi * 4);
        f32x4 sf[4];
        #pragma unroll
        for (int ni = 0; ni < 4; ++ni) sf[ni] = zero4();
        __builtin_amdgcn_s_setprio(1);
        #pragma unroll
        for (int ks = 0; ks < 2; ++ks)
            #pragma unroll
            for (int ni = 0; ni < 4; ++ni) {
                const int rn = ni * 16 + lo;
                const s16x8 kf = *(const s16x8*)&Ks[cur][rn * 64 + (((hi + ks * 4) ^ (rn & 7)) << 3)];
                sf[ni] = mfma16(kf, qf[ks], sf[ni]);
            }
        __builtin_amdgcn_s_setprio(0);

        #pragma unroll
        for (int ni = 0; ni < 4; ++ni) {
            f32x4 wv;
            #pragma unroll
            for (int reg = 0; reg < 4; ++reg) {
                const unsigned int bit = (unsigned int)(mrow >> (ni * 16 + reg)) & 1u;
                const float e = bit ? 0.f : exp2f(sf[ni][reg]);
                wv[reg] = e * il;
            }
            __builtin_nontemporal_store(wv, (f32x4*)(Wrow + (size_t)st * 64 + ni * 16));
            const unsigned int p01 = cvtpk(wv[0], wv[1]);
            const unsigned int p23 = cvtpk(wv[2], wv[3]);
            *(uint2*)((char*)&Ps[wid][0] + lo * 128 + ((ni * 32 + hi * 8) ^ ((lo & 7) << 4))) =
                make_uint2(p01, p23);
        }

        // PV: O[q][d] += P[q][s] V[s][d]
        __builtin_amdgcn_s_setprio(1);
        #pragma unroll
        for (int ks = 0; ks < 2; ++ks) {
            const s16x8 pf = *(const s16x8*)((const char*)&Ps[wid][0] +
                lo * 128 + ((ks * 64 + hi * 16) ^ ((lo & 7) << 4)));
            #pragma unroll
            for (int nd = 0; nd < 4; ++nd) {
                const int rv = nd * 16 + lo;
                const s16x8 vf = *(const s16x8*)&Vs[cur][rv * 64 + (((hi + ks * 4) ^ (rv & 7)) << 3)];
                oacc[nd] = mfma16(pf, vf, oacc[nd]);
            }
        }
        __builtin_amdgcn_s_setprio(0);
        __syncthreads();
    }

    // ---- epilogue: Oh[b*2048 + l][h*64 + d] ----
    #pragma unroll
    for (int nd = 0; nd < 4; ++nd)
        #pragma unroll
        for (int reg = 0; reg < 4; ++reg) {
            const int rl = wid * 16 + hi * 4 + reg;
            const int d = nd * 16 + lo;
            Oh[((size_t)(b * 2048 + l0 + rl) << 10) + hh * 64 + d] = f2bf(oacc[nd][reg]);
        }
}

// ---------------- launch ----------------
extern "C" void kernel_launch(void* const* d_in, const int* in_sizes, int n_in,
                              void* d_out, int out_size, void* d_ws, size_t ws_size,
                              hipStream_t stream) {
    const float* queries = (const float*)d_in[0];
    const float* keys    = (const float*)d_in[1];
    const float* values  = (const float*)d_in[2];
    const unsigned char* mask = (const unsigned char*)d_in[3];
    const float* context = (const float*)d_in[4];
    const float* Wq  = (const float*)d_in[5];  const float* bq  = (const float*)d_in[6];
    const float* Wk  = (const float*)d_in[7];  const float* bk  = (const float*)d_in[8];
    const float* Wv  = (const float*)d_in[9];  const float* bv  = (const float*)d_in[10];
    const float* Wqb = (const float*)d_in[11]; const float* bqb = (const float*)d_in[12];
    const float* Wkg = (const float*)d_in[13]; const float* bkg = (const float*)d_in[14];
    const float* Wvb = (const float*)d_in[15]; const float* bvb = (const float*)d_in[16];
    const float* Wo  = (const float*)d_in[17]; const float* bo  = (const float*)d_in[18];

    unsigned short* ws = (unsigned short*)d_ws;
    unsigned short* xq = ws + OFF_XQ;
    unsigned short* xk = ws + OFF_XK;
    unsigned short* xv = ws + OFF_XV;
    unsigned short* xc = ws + OFF_XC;
    unsigned short* wt = ws + OFF_WT;
    unsigned short* Qh = ws + OFF_QH;
    unsigned short* Kh = ws + OFF_KH;
    unsigned short* Vh = ws + OFF_VH;
    unsigned short* Oh = ws + OFF_OH;
    unsigned short* VhT = ws + OFF_XQ;                               // reuse xq after projections
    unsigned long long* mbits = (unsigned long long*)(ws + OFF_XV);  // reuse xv after V proj

    float* out0  = (float*)d_out;
    float* attnW = out0 + 4194304;

    P4 acts; acts.p[0] = queries; acts.p[1] = keys; acts.p[2] = values; acts.p[3] = context;
    cvt4<<<dim3(2048, 4), 256, 0, stream>>>(acts, xq);

    P7 wts; wts.p[0] = Wq; wts.p[1] = Wqb; wts.p[2] = Wk; wts.p[3] = Wkg;
    wts.p[4] = Wv; wts.p[5] = Wvb; wts.p[6] = Wo;
    wtr<<<dim3(32, 32, 7), 256, 0, stream>>>(wts, wt);

    ProjArgs pa;
    // z=0: Qh = ([Xq|Xc] @ [Wq;Wqb] + bq + bqb) * (0.125*log2e)  -> base-2 softmax
    pa.d[0] = { xq, xc, wt, wt + 1048576u, bq, bqb, Qh, 0.18033688f, 0 };
    // z=1: Vh = [Xv|Xc] @ [Wv;Wvb] + bv + bvb
    pa.d[1] = { xv, xc, wt + 4u * 1048576u, wt + 5u * 1048576u, bv, bvb, Vh, 1.0f, 0 };
    // z=2: Kh = (Xk@Wk + bk) * sigmoid(Xc@Wkg + bkg)
    pa.d[2] = { xk, xc, wt + 2u * 1048576u, wt + 3u * 1048576u, bk, bkg, Kh, 1.0f, 1 };
    proj_all<<<dim3(16, 32, 3), 256, 0, stream>>>(pa);

    vtr<<<dim3(32, 32), 256, 0, stream>>>(Vh, VhT);            // xq region now free
    mpack<<<dim3(32768), 256, 0, stream>>>(mask, mbits);       // xv region now free

    attn_fused<<<dim3(1024), 256, 0, stream>>>(Qh, Kh, VhT, mbits, attnW, Oh);

    gemm_out<<<dim3(16, 32), 256, 0, stream>>>(Oh, wt + 6u * 1048576u, bo, out0);
}